// Round 1
// baseline (12677.440 us; speedup 1.0000x reference)
//
#include <hip/hip_runtime.h>
#include <math.h>

#define HD 1024
#define NBATCH 256
#define VOC 32000
#define TSTEPS 20
#define OUT_ROW 640000LL   // 20*32000, row stride (floats) between b rows in d_out

static __device__ __forceinline__ float sigmoidf_(float v) {
  return 1.0f / (1.0f + expf(-v));
}

// ---------------- embedding + relu: x[b][k] = relu(emb[tok[b]][k]) ----------------
__global__ void embed_relu_k(const float* __restrict__ emb, const int* __restrict__ tok,
                             float* __restrict__ x) {
  int idx = blockIdx.x * 256 + threadIdx.x;      // 65536 = 256*1024/4
  int b = idx >> 8;
  int k4 = (idx & 255) << 2;
  float4 v = *(const float4*)(emb + (size_t)tok[b] * HD + k4);
  v.x = fmaxf(v.x, 0.0f); v.y = fmaxf(v.y, 0.0f);
  v.z = fmaxf(v.z, 0.0f); v.w = fmaxf(v.w, 0.0f);
  *(float4*)(x + (size_t)b * HD + k4) = v;
}

// ---------------- fused GRU input GEMM: gg[b][0:3072] = x @ w_ih^T,
//                  gg[b][3072:6144] = h @ w_hh^T  (biases added later) --------------
// tile 128(M) x 64(N), BK=32, 256 threads, 8x4 micro-tile
__global__ __launch_bounds__(256)
void gemm_gru_k(const float* __restrict__ x, const float* __restrict__ h,
                const float* __restrict__ w_ih, const float* __restrict__ w_hh,
                float* __restrict__ gg) {
  __shared__ float sa[32][132];   // A tile transposed [k][m], pad->16B-aligned rows
  __shared__ float sw[32][68];    // W tile transposed [k][n]
  const int tid = threadIdx.x;
  const int ty = tid >> 4, tx = tid & 15;
  const int lr = tid >> 3;           // 0..31
  const int lc = (tid & 7) << 2;     // 0,4,...,28
  const int n0 = blockIdx.x * 64;
  const int m0 = blockIdx.y * 128;

  const float* A; const float* W; int nc;
  if (n0 < 3072) { A = x; W = w_ih; nc = n0; }
  else           { A = h; W = w_hh; nc = n0 - 3072; }

  float acc[8][4];
  #pragma unroll
  for (int i = 0; i < 8; ++i)
    #pragma unroll
    for (int j = 0; j < 4; ++j) acc[i][j] = 0.0f;

  for (int k0 = 0; k0 < HD; k0 += 32) {
    #pragma unroll
    for (int p = 0; p < 4; ++p) {
      int row = lr + (p << 5);       // 0..127
      float4 va = *(const float4*)(A + (size_t)(m0 + row) * HD + k0 + lc);
      sa[lc + 0][row] = va.x; sa[lc + 1][row] = va.y;
      sa[lc + 2][row] = va.z; sa[lc + 3][row] = va.w;
    }
    #pragma unroll
    for (int p = 0; p < 2; ++p) {
      int row = lr + (p << 5);       // 0..63
      float4 vw = *(const float4*)(W + (size_t)(nc + row) * HD + k0 + lc);
      sw[lc + 0][row] = vw.x; sw[lc + 1][row] = vw.y;
      sw[lc + 2][row] = vw.z; sw[lc + 3][row] = vw.w;
    }
    __syncthreads();
    #pragma unroll
    for (int kk = 0; kk < 32; ++kk) {
      float4 a0 = *(const float4*)&sa[kk][ty << 3];
      float4 a1 = *(const float4*)&sa[kk][(ty << 3) + 4];
      float4 w4 = *(const float4*)&sw[kk][tx << 2];
      float av[8] = {a0.x, a0.y, a0.z, a0.w, a1.x, a1.y, a1.z, a1.w};
      float wv[4] = {w4.x, w4.y, w4.z, w4.w};
      #pragma unroll
      for (int i = 0; i < 8; ++i)
        #pragma unroll
        for (int j = 0; j < 4; ++j) acc[i][j] += av[i] * wv[j];
    }
    __syncthreads();
  }
  #pragma unroll
  for (int i = 0; i < 8; ++i) {
    float4 r; r.x = acc[i][0]; r.y = acc[i][1]; r.z = acc[i][2]; r.w = acc[i][3];
    *(float4*)(gg + (size_t)(m0 + (ty << 3) + i) * 6144 + n0 + (tx << 2)) = r;
  }
}

// ---------------- GRU gates: h' = (1-z)*n + z*h ----------------
__global__ void gru_gates_k(const float* __restrict__ gg,
                            const float* __restrict__ b_ih, const float* __restrict__ b_hh,
                            const float* __restrict__ h_old, float* __restrict__ h_new) {
  int idx = blockIdx.x * 256 + threadIdx.x;   // 65536
  int b = idx >> 8;
  int k4 = (idx & 255) << 2;
  const float* g = gg + (size_t)b * 6144;
  float4 gir = *(const float4*)(g + k4);
  float4 giz = *(const float4*)(g + 1024 + k4);
  float4 gin = *(const float4*)(g + 2048 + k4);
  float4 ghr = *(const float4*)(g + 3072 + k4);
  float4 ghz = *(const float4*)(g + 4096 + k4);
  float4 ghn = *(const float4*)(g + 5120 + k4);
  float4 bir = *(const float4*)(b_ih + k4);
  float4 biz = *(const float4*)(b_ih + 1024 + k4);
  float4 bin = *(const float4*)(b_ih + 2048 + k4);
  float4 bhr = *(const float4*)(b_hh + k4);
  float4 bhz = *(const float4*)(b_hh + 1024 + k4);
  float4 bhn = *(const float4*)(b_hh + 2048 + k4);
  float4 ho  = *(const float4*)(h_old + (size_t)b * HD + k4);
  float4 o;
  #define GATE(c) { \
    float rr = sigmoidf_(gir.c + bir.c + ghr.c + bhr.c); \
    float zz = sigmoidf_(giz.c + biz.c + ghz.c + bhz.c); \
    float nn = tanhf(gin.c + bin.c + rr * (ghn.c + bhn.c)); \
    o.c = (1.0f - zz) * nn + zz * ho.c; }
  GATE(x) GATE(y) GATE(z) GATE(w)
  #undef GATE
  *(float4*)(h_new + (size_t)b * HD + k4) = o;
}

// ---------------- logits GEMM: out[b][v] = x[b]·out_w[v] + out_b[v] ----------------
// same tiling as gemm_gru_k; writes with OUT_ROW stride into d_out (+ t*VOC offset)
__global__ __launch_bounds__(256)
void gemm_logits_k(const float* __restrict__ x, const float* __restrict__ wv_,
                   const float* __restrict__ bias, float* __restrict__ out) {
  __shared__ float sa[32][132];
  __shared__ float sw[32][68];
  const int tid = threadIdx.x;
  const int ty = tid >> 4, tx = tid & 15;
  const int lr = tid >> 3;
  const int lc = (tid & 7) << 2;
  const int n0 = blockIdx.x * 64;
  const int m0 = blockIdx.y * 128;

  float acc[8][4];
  #pragma unroll
  for (int i = 0; i < 8; ++i)
    #pragma unroll
    for (int j = 0; j < 4; ++j) acc[i][j] = 0.0f;

  for (int k0 = 0; k0 < HD; k0 += 32) {
    #pragma unroll
    for (int p = 0; p < 4; ++p) {
      int row = lr + (p << 5);
      float4 va = *(const float4*)(x + (size_t)(m0 + row) * HD + k0 + lc);
      sa[lc + 0][row] = va.x; sa[lc + 1][row] = va.y;
      sa[lc + 2][row] = va.z; sa[lc + 3][row] = va.w;
    }
    #pragma unroll
    for (int p = 0; p < 2; ++p) {
      int row = lr + (p << 5);
      float4 vw = *(const float4*)(wv_ + (size_t)(n0 + row) * HD + k0 + lc);
      sw[lc + 0][row] = vw.x; sw[lc + 1][row] = vw.y;
      sw[lc + 2][row] = vw.z; sw[lc + 3][row] = vw.w;
    }
    __syncthreads();
    #pragma unroll
    for (int kk = 0; kk < 32; ++kk) {
      float4 a0 = *(const float4*)&sa[kk][ty << 3];
      float4 a1 = *(const float4*)&sa[kk][(ty << 3) + 4];
      float4 w4 = *(const float4*)&sw[kk][tx << 2];
      float av[8] = {a0.x, a0.y, a0.z, a0.w, a1.x, a1.y, a1.z, a1.w};
      float wvv[4] = {w4.x, w4.y, w4.z, w4.w};
      #pragma unroll
      for (int i = 0; i < 8; ++i)
        #pragma unroll
        for (int j = 0; j < 4; ++j) acc[i][j] += av[i] * wvv[j];
    }
    __syncthreads();
  }
  float4 bv = *(const float4*)(bias + n0 + (tx << 2));
  #pragma unroll
  for (int i = 0; i < 8; ++i) {
    float4 r;
    r.x = acc[i][0] + bv.x; r.y = acc[i][1] + bv.y;
    r.z = acc[i][2] + bv.z; r.w = acc[i][3] + bv.w;
    *(float4*)(out + (size_t)(m0 + (ty << 3) + i) * OUT_ROW + n0 + (tx << 2)) = r;
  }
}

// ---------------- per-row argmax (first-index ties) + logsumexp ----------------
__global__ __launch_bounds__(256)
void row_reduce_k(const float* __restrict__ lg, int* __restrict__ tok,
                  float* __restrict__ lse) {
  __shared__ float sv[256];
  __shared__ int   si[256];
  __shared__ float ss[256];
  const int b = blockIdx.x;
  const int tid = threadIdx.x;
  const float* row = lg + (size_t)b * OUT_ROW;
  float vmax = -3.4e38f; int imax = 0x3fffffff;
  for (int i = tid; i < VOC; i += 256) {
    float v = row[i];
    if (v > vmax) { vmax = v; imax = i; }   // per-thread i increasing -> first wins
  }
  sv[tid] = vmax; si[tid] = imax;
  __syncthreads();
  for (int off = 128; off; off >>= 1) {
    if (tid < off) {
      float v2 = sv[tid + off]; int i2 = si[tid + off];
      if (v2 > sv[tid] || (v2 == sv[tid] && i2 < si[tid])) { sv[tid] = v2; si[tid] = i2; }
    }
    __syncthreads();
  }
  float gmax = sv[0];
  float s = 0.0f;
  for (int i = tid; i < VOC; i += 256) s += expf(row[i] - gmax);
  ss[tid] = s;
  __syncthreads();
  for (int off = 128; off; off >>= 1) {
    if (tid < off) ss[tid] += ss[tid + off];
    __syncthreads();
  }
  if (tid == 0) { tok[b] = si[0]; lse[b] = gmax + logf(ss[0]); }
}

// ---------------- log_softmax fixup: out -= lse[b] (in place, L2-hot) ----------------
__global__ void sub_lse_k(float* __restrict__ lg, const float* __restrict__ lse) {
  int idx = blockIdx.x * 256 + threadIdx.x;    // 2,048,000 = 256 * 8000
  int b = idx / 8000;
  int r = idx - b * 8000;
  float l = lse[b];
  float4* p = (float4*)(lg + (size_t)b * OUT_ROW) + r;
  float4 v = *p;
  v.x -= l; v.y -= l; v.z -= l; v.w -= l;
  *p = v;
}

extern "C" void kernel_launch(void* const* d_in, const int* in_sizes, int n_in,
                              void* d_out, int out_size, void* d_ws, size_t ws_size,
                              hipStream_t stream) {
  (void)in_sizes; (void)n_in; (void)out_size; (void)ws_size;
  const float* enc_hidden = (const float*)d_in[1];   // [4,256,1024]
  const float* emb   = (const float*)d_in[2];        // [32000,1024]
  const float* w_ih  = (const float*)d_in[3];        // [4,3072,1024]
  const float* w_hh  = (const float*)d_in[4];        // [4,3072,1024]
  const float* b_ih  = (const float*)d_in[5];        // [4,3072]
  const float* b_hh  = (const float*)d_in[6];        // [4,3072]
  const float* out_w = (const float*)d_in[7];        // [32000,1024]
  const float* out_b = (const float*)d_in[8];        // [32000]
  float* out = (float*)d_out;

  char* wsp = (char*)d_ws;
  float* hbuf = (float*)wsp; wsp += (size_t)2 * 4 * NBATCH * HD * 4;  // double-buffered h
  float* xbuf = (float*)wsp; wsp += (size_t)NBATCH * HD * 4;          // embed output
  float* gg   = (float*)wsp; wsp += (size_t)NBATCH * 6144 * 4;        // gi|gh scratch
  int*   tok  = (int*)wsp;   wsp += 1024;
  float* lse  = (float*)wsp; wsp += 1024;

  const size_t HSZ = (size_t)4 * NBATCH * HD;   // floats per parity buffer

  hipMemcpyAsync(hbuf, enc_hidden, HSZ * 4, hipMemcpyDeviceToDevice, stream);
  hipMemsetAsync(tok, 0, NBATCH * 4, stream);

  int p = 0;
  for (int t = 0; t < TSTEPS; ++t) {
    float* hp = hbuf + (size_t)p * HSZ;
    float* hn = hbuf + (size_t)(1 - p) * HSZ;

    embed_relu_k<<<256, 256, 0, stream>>>(emb, tok, xbuf);

    const float* lin = xbuf;
    for (int l = 0; l < 4; ++l) {
      gemm_gru_k<<<dim3(96, 2), 256, 0, stream>>>(
          lin, hp + (size_t)l * NBATCH * HD,
          w_ih + (size_t)l * 3072 * HD, w_hh + (size_t)l * 3072 * HD, gg);
      gru_gates_k<<<256, 256, 0, stream>>>(
          gg, b_ih + l * 3072, b_hh + l * 3072,
          hp + (size_t)l * NBATCH * HD, hn + (size_t)l * NBATCH * HD);
      lin = hn + (size_t)l * NBATCH * HD;
    }

    float* lg = out + (size_t)t * VOC;
    gemm_logits_k<<<dim3(500, 2), 256, 0, stream>>>(lin, out_w, out_b, lg);
    row_reduce_k<<<NBATCH, 256, 0, stream>>>(lg, tok, lse);
    sub_lse_k<<<8000, 256, 0, stream>>>(lg, lse);

    p ^= 1;
  }

  // after an even number of steps the final h sits in parity-0 buffer
  hipMemcpyAsync(out + (size_t)NBATCH * TSTEPS * VOC, hbuf, HSZ * 4,
                 hipMemcpyDeviceToDevice, stream);
}

// Round 2
// 8628.164 us; speedup vs baseline: 1.4693x; 1.4693x over previous
//
#include <hip/hip_runtime.h>
#include <math.h>

#define HD 1024
#define NBATCH 256
#define VOC 32000
#define TSTEPS 20
#define OUT_ROW 640000LL   // 20*32000, row stride (floats) between b rows in d_out

typedef _Float16 f16;
typedef __attribute__((ext_vector_type(8))) _Float16 f16x8;
typedef __attribute__((ext_vector_type(4))) float f32x4;

#define GLOBAL_AS __attribute__((address_space(1)))
#define LDS_AS    __attribute__((address_space(3)))

static __device__ __forceinline__ float sigmoidf_(float v) {
  return 1.0f / (1.0f + expf(-v));
}

// ---------------- embedding + relu ----------------
__global__ void embed_relu_k(const float* __restrict__ emb, const int* __restrict__ tok,
                             float* __restrict__ x) {
  int idx = blockIdx.x * 256 + threadIdx.x;      // 65536 = 256*1024/4
  int b = idx >> 8;
  int k4 = (idx & 255) << 2;
  float4 v = *(const float4*)(emb + (size_t)tok[b] * HD + k4);
  v.x = fmaxf(v.x, 0.0f); v.y = fmaxf(v.y, 0.0f);
  v.z = fmaxf(v.z, 0.0f); v.w = fmaxf(v.w, 0.0f);
  *(float4*)(x + (size_t)b * HD + k4) = v;
}

// ---------------- fp32 -> f16 convert (8 elems/thread, grid-stride) ----------------
__global__ void f32_to_f16_k(const float* __restrict__ in, f16* __restrict__ out, long n8) {
  long i = (long)blockIdx.x * 256 + threadIdx.x;
  long stride = (long)gridDim.x * 256;
  for (; i < n8; i += stride) {
    float4 a = *((const float4*)in + i * 2);
    float4 b = *((const float4*)in + i * 2 + 1);
    f16x8 o;
    o[0] = (f16)a.x; o[1] = (f16)a.y; o[2] = (f16)a.z; o[3] = (f16)a.w;
    o[4] = (f16)b.x; o[5] = (f16)b.y; o[6] = (f16)b.z; o[7] = (f16)b.w;
    *((f16x8*)out + i) = o;
  }
}

// ---------------- GRU GEMM: 64x64 tile, K-split x2 ----------------
// gg2[z][b][0:3072] = x @ w_ih^T (K-half z), gg2[z][b][3072:6144] = h @ w_hh^T
__global__ __launch_bounds__(256)
void gemm_gru64_k(const float* __restrict__ x, const float* __restrict__ h,
                  const float* __restrict__ w_ih, const float* __restrict__ w_hh,
                  float* __restrict__ gg2) {
  __shared__ float sa[32][68];
  __shared__ float sw[32][68];
  const int tid = threadIdx.x;
  const int ty = tid >> 4, tx = tid & 15;
  const int lr = tid >> 3;           // 0..31
  const int lc = (tid & 7) << 2;     // 0,4,...,28
  const int n0g = blockIdx.x * 64;   // 0..6080
  const int m0 = blockIdx.y * 64;    // 0..192
  const int kb = blockIdx.z * 512;

  const float* A; const float* W; int nc;
  if (n0g < 3072) { A = x; W = w_ih; nc = n0g; }
  else            { A = h; W = w_hh; nc = n0g - 3072; }

  float acc[4][4];
  #pragma unroll
  for (int i = 0; i < 4; ++i)
    #pragma unroll
    for (int j = 0; j < 4; ++j) acc[i][j] = 0.0f;

  for (int k0 = kb; k0 < kb + 512; k0 += 32) {
    #pragma unroll
    for (int p = 0; p < 2; ++p) {
      int row = lr + (p << 5);       // 0..63
      float4 va = *(const float4*)(A + (size_t)(m0 + row) * HD + k0 + lc);
      sa[lc + 0][row] = va.x; sa[lc + 1][row] = va.y;
      sa[lc + 2][row] = va.z; sa[lc + 3][row] = va.w;
      float4 vw = *(const float4*)(W + (size_t)(nc + row) * HD + k0 + lc);
      sw[lc + 0][row] = vw.x; sw[lc + 1][row] = vw.y;
      sw[lc + 2][row] = vw.z; sw[lc + 3][row] = vw.w;
    }
    __syncthreads();
    #pragma unroll
    for (int kk = 0; kk < 32; ++kk) {
      float4 a4 = *(const float4*)&sa[kk][ty << 2];
      float4 w4 = *(const float4*)&sw[kk][tx << 2];
      float av[4] = {a4.x, a4.y, a4.z, a4.w};
      float wv[4] = {w4.x, w4.y, w4.z, w4.w};
      #pragma unroll
      for (int i = 0; i < 4; ++i)
        #pragma unroll
        for (int j = 0; j < 4; ++j) acc[i][j] += av[i] * wv[j];
    }
    __syncthreads();
  }
  float* outp = gg2 + (size_t)blockIdx.z * NBATCH * 6144;
  #pragma unroll
  for (int i = 0; i < 4; ++i) {
    float4 r; r.x = acc[i][0]; r.y = acc[i][1]; r.z = acc[i][2]; r.w = acc[i][3];
    *(float4*)(outp + (size_t)(m0 + (ty << 2) + i) * 6144 + n0g + (tx << 2)) = r;
  }
}

// ---------------- GRU gates over K-split partials ----------------
static __device__ __forceinline__ float4 add4_(float4 a, float4 b) {
  float4 r; r.x = a.x + b.x; r.y = a.y + b.y; r.z = a.z + b.z; r.w = a.w + b.w; return r;
}
__global__ void gru_gates2_k(const float* __restrict__ gg2,
                             const float* __restrict__ b_ih, const float* __restrict__ b_hh,
                             const float* __restrict__ h_old, float* __restrict__ h_new) {
  int idx = blockIdx.x * 256 + threadIdx.x;   // 65536
  int b = idx >> 8;
  int k4 = (idx & 255) << 2;
  const float* g0 = gg2 + (size_t)b * 6144;
  const float* g1 = gg2 + (size_t)NBATCH * 6144 + (size_t)b * 6144;
  #define LD2(off) add4_(*(const float4*)(g0 + (off) + k4), *(const float4*)(g1 + (off) + k4))
  float4 gir = LD2(0);
  float4 giz = LD2(1024);
  float4 gin = LD2(2048);
  float4 ghr = LD2(3072);
  float4 ghz = LD2(4096);
  float4 ghn = LD2(5120);
  #undef LD2
  float4 bir = *(const float4*)(b_ih + k4);
  float4 biz = *(const float4*)(b_ih + 1024 + k4);
  float4 bin = *(const float4*)(b_ih + 2048 + k4);
  float4 bhr = *(const float4*)(b_hh + k4);
  float4 bhz = *(const float4*)(b_hh + 1024 + k4);
  float4 bhn = *(const float4*)(b_hh + 2048 + k4);
  float4 ho  = *(const float4*)(h_old + (size_t)b * HD + k4);
  float4 o;
  #define GATE(c) { \
    float rr = sigmoidf_(gir.c + bir.c + ghr.c + bhr.c); \
    float zz = sigmoidf_(giz.c + biz.c + ghz.c + bhz.c); \
    float nn = tanhf(gin.c + bin.c + rr * (ghn.c + bhn.c)); \
    o.c = (1.0f - zz) * nn + zz * ho.c; }
  GATE(x) GATE(y) GATE(z) GATE(w)
  #undef GATE
  *(float4*)(h_new + (size_t)b * HD + k4) = o;
}

// ---------------- logits GEMM, f16 MFMA: 128x128 tile, 4 waves, BK=32 ----------------
// A (x_f16, [256][1024]) read register-direct; B (w_f16, [32000][1024]) staged to LDS
// as 16B atoms: atom index = kg*128 + n  (kg = k-group 0..3, n = col 0..127).
__global__ __launch_bounds__(256)
void gemm_logits_f16_k(const f16* __restrict__ xf, const f16* __restrict__ wf,
                       const float* __restrict__ bias, float* __restrict__ out) {
  __shared__ f16 lb_raw[4096];                 // 512 atoms * 8 f16 = 8 KB
  f16x8* lbv = (f16x8*)lb_raw;
  const int tid = threadIdx.x;
  const int lane = tid & 63;
  const int wave = tid >> 6;                   // 0..3
  const int wm = wave >> 1, wn = wave & 1;
  const int l15 = lane & 15, l4 = lane >> 4;   // l4 = 0..3
  const int n0 = blockIdx.x * 128;
  const int m0 = blockIdx.y * 128;

  f32x4 acc[4][4];
  #pragma unroll
  for (int mi = 0; mi < 4; ++mi)
    #pragma unroll
    for (int ni = 0; ni < 4; ++ni) acc[mi][ni] = (f32x4){0.f, 0.f, 0.f, 0.f};

  f16x8 a_cur[4], a_nxt[4];

  // stage tile k0: 8 x global_load_lds (1 KB each), 2 per wave
  #define STAGE(k0) { \
    _Pragma("unroll") \
    for (int jj = 0; jj < 2; ++jj) { \
      int j = wave * 2 + jj; \
      int a = j * 64 + lane; \
      int n = a & 127, kg = a >> 7; \
      const f16* src = wf + (size_t)(n0 + n) * 1024 + (k0) + kg * 8; \
      __builtin_amdgcn_global_load_lds((const GLOBAL_AS void*)src, \
          (LDS_AS void*)(lb_raw + (size_t)j * 512), 16, 0, 0); \
    } }
  #define LOADA(k0, dst) { \
    _Pragma("unroll") \
    for (int mi = 0; mi < 4; ++mi) { \
      int row = m0 + wm * 64 + mi * 16 + l15; \
      dst[mi] = *(const f16x8*)(xf + (size_t)row * 1024 + (k0) + l4 * 8); \
    } }

  STAGE(0);
  LOADA(0, a_cur);
  __syncthreads();   // stage 0 complete (compiler drains vmcnt before barrier)

  for (int kt = 0; kt < 32; ++kt) {
    f16x8 b[4];
    #pragma unroll
    for (int ni = 0; ni < 4; ++ni) {
      int nl = wn * 64 + ni * 16 + l15;
      b[ni] = lbv[l4 * 128 + nl];
    }
    if (kt < 31) LOADA((kt + 1) * 32, a_nxt);
    __syncthreads();                 // tile-kt reads done -> safe to overwrite
    if (kt < 31) STAGE((kt + 1) * 32);
    #pragma unroll
    for (int mi = 0; mi < 4; ++mi)
      #pragma unroll
      for (int ni = 0; ni < 4; ++ni)
        acc[mi][ni] = __builtin_amdgcn_mfma_f32_16x16x32_f16(a_cur[mi], b[ni], acc[mi][ni], 0, 0, 0);
    __syncthreads();                 // stage kt+1 complete
    #pragma unroll
    for (int mi = 0; mi < 4; ++mi) a_cur[mi] = a_nxt[mi];
  }
  #undef STAGE
  #undef LOADA

  #pragma unroll
  for (int mi = 0; mi < 4; ++mi)
    #pragma unroll
    for (int ni = 0; ni < 4; ++ni) {
      const int col = n0 + wn * 64 + ni * 16 + l15;
      const float bv = bias[col];
      #pragma unroll
      for (int r = 0; r < 4; ++r) {
        const int row = m0 + wm * 64 + mi * 16 + l4 * 4 + r;
        out[(size_t)row * OUT_ROW + col] = acc[mi][ni][r] + bv;
      }
    }
}

// ---------------- row reduce: approx max, lse, candidate list ----------------
__global__ __launch_bounds__(256)
void row_reduce_cand_k(const float* __restrict__ lg, float* __restrict__ lse,
                       int* __restrict__ cand, int* __restrict__ cnt) {
  __shared__ float sv[256];
  __shared__ float ss[256];
  __shared__ int scnt;
  const int b = blockIdx.x;
  const int tid = threadIdx.x;
  const float* row = lg + (size_t)b * OUT_ROW;
  float vmax = -3.4e38f;
  for (int i = tid; i < VOC; i += 256) vmax = fmaxf(vmax, row[i]);
  sv[tid] = vmax;
  if (tid == 0) scnt = 0;
  __syncthreads();
  for (int off = 128; off; off >>= 1) {
    if (tid < off) sv[tid] = fmaxf(sv[tid], sv[tid + off]);
    __syncthreads();
  }
  float gmax = sv[0];
  float thr = gmax - 0.125f;   // f16-GEMM error bound ~0.01 << 0.125
  float s = 0.0f;
  for (int i = tid; i < VOC; i += 256) {
    float v = row[i];
    s += expf(v - gmax);
    if (v >= thr) {
      int p = atomicAdd(&scnt, 1);
      if (p < 64) cand[b * 64 + p] = i;
    }
  }
  ss[tid] = s;
  __syncthreads();
  for (int off = 128; off; off >>= 1) {
    if (tid < off) ss[tid] += ss[tid + off];
    __syncthreads();
  }
  if (tid == 0) { lse[b] = gmax + logf(ss[0]); cnt[b] = scnt < 64 ? scnt : 64; }
}

// ---------------- exact argmax rescue (fp64 dot over candidates) ----------------
__global__ __launch_bounds__(256)
void rescue_k(const float* __restrict__ x, const float* __restrict__ w,
              const float* __restrict__ ob, const int* __restrict__ cand,
              const int* __restrict__ cnt, int* __restrict__ tok) {
  __shared__ double sd[256];
  __shared__ double s_best;
  __shared__ int s_bi;
  const int b = blockIdx.x;
  const int tid = threadIdx.x;
  const int c = cnt[b];
  if (tid == 0) { s_best = -1.0e300; s_bi = 0x7fffffff; }
  __syncthreads();
  for (int j = 0; j < c; ++j) {
    const int idx = cand[b * 64 + j];
    double p = 0.0;
    const float* xr = x + (size_t)b * HD;
    const float* wr = w + (size_t)idx * HD;
    for (int k = tid; k < HD; k += 256) p += (double)xr[k] * (double)wr[k];
    sd[tid] = p;
    __syncthreads();
    for (int off = 128; off; off >>= 1) {
      if (tid < off) sd[tid] += sd[tid + off];
      __syncthreads();
    }
    if (tid == 0) {
      double tot = sd[0] + (double)ob[idx];
      if (tot > s_best || (tot == s_best && idx < s_bi)) { s_best = tot; s_bi = idx; }
    }
    __syncthreads();
  }
  if (tid == 0) tok[b] = s_bi;
}

// ---------------- fp32 fallback logits GEMM (round-1, kept for small ws) ----------
__global__ __launch_bounds__(256)
void gemm_logits_k(const float* __restrict__ x, const float* __restrict__ wv_,
                   const float* __restrict__ bias, float* __restrict__ out) {
  __shared__ float sa[32][132];
  __shared__ float sw[32][68];
  const int tid = threadIdx.x;
  const int ty = tid >> 4, tx = tid & 15;
  const int lr = tid >> 3;
  const int lc = (tid & 7) << 2;
  const int n0 = blockIdx.x * 64;
  const int m0 = blockIdx.y * 128;
  float acc[8][4];
  #pragma unroll
  for (int i = 0; i < 8; ++i)
    #pragma unroll
    for (int j = 0; j < 4; ++j) acc[i][j] = 0.0f;
  for (int k0 = 0; k0 < HD; k0 += 32) {
    #pragma unroll
    for (int p = 0; p < 4; ++p) {
      int row = lr + (p << 5);
      float4 va = *(const float4*)(x + (size_t)(m0 + row) * HD + k0 + lc);
      sa[lc + 0][row] = va.x; sa[lc + 1][row] = va.y;
      sa[lc + 2][row] = va.z; sa[lc + 3][row] = va.w;
    }
    #pragma unroll
    for (int p = 0; p < 2; ++p) {
      int row = lr + (p << 5);
      float4 vw = *(const float4*)(wv_ + (size_t)(n0 + row) * HD + k0 + lc);
      sw[lc + 0][row] = vw.x; sw[lc + 1][row] = vw.y;
      sw[lc + 2][row] = vw.z; sw[lc + 3][row] = vw.w;
    }
    __syncthreads();
    #pragma unroll
    for (int kk = 0; kk < 32; ++kk) {
      float4 a0 = *(const float4*)&sa[kk][ty << 3];
      float4 a1 = *(const float4*)&sa[kk][(ty << 3) + 4];
      float4 w4 = *(const float4*)&sw[kk][tx << 2];
      float av[8] = {a0.x, a0.y, a0.z, a0.w, a1.x, a1.y, a1.z, a1.w};
      float wvv[4] = {w4.x, w4.y, w4.z, w4.w};
      #pragma unroll
      for (int i = 0; i < 8; ++i)
        #pragma unroll
        for (int j = 0; j < 4; ++j) acc[i][j] += av[i] * wvv[j];
    }
    __syncthreads();
  }
  float4 bv = *(const float4*)(bias + n0 + (tx << 2));
  #pragma unroll
  for (int i = 0; i < 8; ++i) {
    float4 r;
    r.x = acc[i][0] + bv.x; r.y = acc[i][1] + bv.y;
    r.z = acc[i][2] + bv.z; r.w = acc[i][3] + bv.w;
    *(float4*)(out + (size_t)(m0 + (ty << 3) + i) * OUT_ROW + n0 + (tx << 2)) = r;
  }
}

// ---------------- fallback: exact argmax + lse ----------------
__global__ __launch_bounds__(256)
void row_reduce_k(const float* __restrict__ lg, int* __restrict__ tok,
                  float* __restrict__ lse) {
  __shared__ float sv[256];
  __shared__ int   si[256];
  __shared__ float ss[256];
  const int b = blockIdx.x;
  const int tid = threadIdx.x;
  const float* row = lg + (size_t)b * OUT_ROW;
  float vmax = -3.4e38f; int imax = 0x3fffffff;
  for (int i = tid; i < VOC; i += 256) {
    float v = row[i];
    if (v > vmax) { vmax = v; imax = i; }
  }
  sv[tid] = vmax; si[tid] = imax;
  __syncthreads();
  for (int off = 128; off; off >>= 1) {
    if (tid < off) {
      float v2 = sv[tid + off]; int i2 = si[tid + off];
      if (v2 > sv[tid] || (v2 == sv[tid] && i2 < si[tid])) { sv[tid] = v2; si[tid] = i2; }
    }
    __syncthreads();
  }
  float gmax = sv[0];
  float s = 0.0f;
  for (int i = tid; i < VOC; i += 256) s += expf(row[i] - gmax);
  ss[tid] = s;
  __syncthreads();
  for (int off = 128; off; off >>= 1) {
    if (tid < off) ss[tid] += ss[tid + off];
    __syncthreads();
  }
  if (tid == 0) { tok[b] = si[0]; lse[b] = gmax + logf(ss[0]); }
}

// ---------------- log_softmax fixup ----------------
__global__ void sub_lse_k(float* __restrict__ lg, const float* __restrict__ lse) {
  int idx = blockIdx.x * 256 + threadIdx.x;    // 2,048,000
  int b = idx / 8000;
  int r = idx - b * 8000;
  float l = lse[b];
  float4* p = (float4*)(lg + (size_t)b * OUT_ROW) + r;
  float4 v = *p;
  v.x -= l; v.y -= l; v.z -= l; v.w -= l;
  *p = v;
}

extern "C" void kernel_launch(void* const* d_in, const int* in_sizes, int n_in,
                              void* d_out, int out_size, void* d_ws, size_t ws_size,
                              hipStream_t stream) {
  (void)in_sizes; (void)n_in; (void)out_size;
  const float* enc_hidden = (const float*)d_in[1];   // [4,256,1024]
  const float* emb   = (const float*)d_in[2];        // [32000,1024]
  const float* w_ih  = (const float*)d_in[3];        // [4,3072,1024]
  const float* w_hh  = (const float*)d_in[4];        // [4,3072,1024]
  const float* b_ih  = (const float*)d_in[5];        // [4,3072]
  const float* b_hh  = (const float*)d_in[6];        // [4,3072]
  const float* out_w = (const float*)d_in[7];        // [32000,1024]
  const float* out_b = (const float*)d_in[8];        // [32000]
  float* out = (float*)d_out;

  size_t off = 0;
  char* base = (char*)d_ws;
  #define WSALLOC(bytes) ((void*)(base + off)); off += (((size_t)(bytes)) + 255) & ~(size_t)255
  float* hbuf = (float*) WSALLOC((size_t)2 * 4 * NBATCH * HD * 4);
  float* gg2  = (float*) WSALLOC((size_t)2 * NBATCH * 6144 * 4);
  float* xbuf = (float*) WSALLOC((size_t)NBATCH * HD * 4);
  f16*   xf16 = (f16*)   WSALLOC((size_t)NBATCH * HD * 2);
  f16*   wf16 = (f16*)   WSALLOC((size_t)VOC * HD * 2);
  int*   tok  = (int*)   WSALLOC(1024);
  float* lse  = (float*) WSALLOC(1024);
  int*   cand = (int*)   WSALLOC((size_t)NBATCH * 64 * 4);
  int*   cnt  = (int*)   WSALLOC(1024);
  #undef WSALLOC
  const bool f16path = (off <= ws_size);

  const size_t HSZ = (size_t)4 * NBATCH * HD;

  hipMemcpyAsync(hbuf, enc_hidden, HSZ * 4, hipMemcpyDeviceToDevice, stream);
  hipMemsetAsync(tok, 0, NBATCH * 4, stream);

  if (f16path) {
    // convert out_w to f16 once per call (deterministic, no caching)
    f32_to_f16_k<<<2048, 256, 0, stream>>>(out_w, wf16, (long)VOC * HD / 8);
  }

  int p = 0;
  for (int t = 0; t < TSTEPS; ++t) {
    float* hp = hbuf + (size_t)p * HSZ;
    float* hn = hbuf + (size_t)(1 - p) * HSZ;

    embed_relu_k<<<256, 256, 0, stream>>>(emb, tok, xbuf);

    const float* lin = xbuf;
    for (int l = 0; l < 4; ++l) {
      gemm_gru64_k<<<dim3(96, 4, 2), 256, 0, stream>>>(
          lin, hp + (size_t)l * NBATCH * HD,
          w_ih + (size_t)l * 3072 * HD, w_hh + (size_t)l * 3072 * HD, gg2);
      gru_gates2_k<<<256, 256, 0, stream>>>(
          gg2, b_ih + l * 3072, b_hh + l * 3072,
          hp + (size_t)l * NBATCH * HD, hn + (size_t)l * NBATCH * HD);
      lin = hn + (size_t)l * NBATCH * HD;
    }

    float* lg = out + (size_t)t * VOC;
    if (f16path) {
      f32_to_f16_k<<<128, 256, 0, stream>>>(lin, xf16, (long)NBATCH * HD / 8);
      gemm_logits_f16_k<<<dim3(250, 2), 256, 0, stream>>>(xf16, wf16, out_b, lg);
      row_reduce_cand_k<<<NBATCH, 256, 0, stream>>>(lg, lse, cand, cnt);
      rescue_k<<<NBATCH, 256, 0, stream>>>(lin, out_w, out_b, cand, cnt, tok);
    } else {
      gemm_logits_k<<<dim3(500, 2), 256, 0, stream>>>(lin, out_w, out_b, lg);
      row_reduce_k<<<NBATCH, 256, 0, stream>>>(lg, tok, lse);
    }
    sub_lse_k<<<8000, 256, 0, stream>>>(lg, lse);

    p ^= 1;
  }

  hipMemcpyAsync(out + (size_t)NBATCH * TSTEPS * VOC, hbuf, HSZ * 4,
                 hipMemcpyDeviceToDevice, stream);
}

// Round 3
// 8524.593 us; speedup vs baseline: 1.4872x; 1.0121x over previous
//
#include <hip/hip_runtime.h>
#include <math.h>

#define HD 1024
#define NBATCH 256
#define VOC 32000
#define TSTEPS 20
#define OUT_ROW 640000LL   // 20*32000, row stride (floats) between b rows in d_out
#define BH ((size_t)NBATCH * HD)

typedef _Float16 f16;
typedef __attribute__((ext_vector_type(4))) _Float16 f16x4;
typedef __attribute__((ext_vector_type(8))) _Float16 f16x8;
typedef __attribute__((ext_vector_type(4))) float f32x4;

#define GLOBAL_AS __attribute__((address_space(1)))
#define LDS_AS    __attribute__((address_space(3)))

static __device__ __forceinline__ float sigmoidf_(float v) {
  return 1.0f / (1.0f + expf(-v));
}

// ================= conversion kernels =================

// fp32 -> f16 (8 elems/thread, grid-stride)
__global__ void f32_to_f16_k(const float* __restrict__ in, f16* __restrict__ out, long n8) {
  long i = (long)blockIdx.x * 256 + threadIdx.x;
  long stride = (long)gridDim.x * 256;
  for (; i < n8; i += stride) {
    float4 a = *((const float4*)in + i * 2);
    float4 b = *((const float4*)in + i * 2 + 1);
    f16x8 o;
    o[0] = (f16)a.x; o[1] = (f16)a.y; o[2] = (f16)a.z; o[3] = (f16)a.w;
    o[4] = (f16)b.x; o[5] = (f16)b.y; o[6] = (f16)b.z; o[7] = (f16)b.w;
    *((f16x8*)out + i) = o;
  }
}

// fp32 -> split f16 (hi = f16(v), lo = f16(v - hi)), 8 elems/thread
__global__ void split_f32_k(const float* __restrict__ in, f16* __restrict__ hi,
                            f16* __restrict__ lo, long n8) {
  long i = (long)blockIdx.x * 256 + threadIdx.x;
  long stride = (long)gridDim.x * 256;
  for (; i < n8; i += stride) {
    float4 a = *((const float4*)in + i * 2);
    float4 b = *((const float4*)in + i * 2 + 1);
    float v[8] = {a.x, a.y, a.z, a.w, b.x, b.y, b.z, b.w};
    f16x8 h8, l8;
    #pragma unroll
    for (int j = 0; j < 8; ++j) {
      f16 h = (f16)v[j];
      h8[j] = h;
      l8[j] = (f16)(v[j] - (float)h);
    }
    *((f16x8*)hi + i) = h8;
    *((f16x8*)lo + i) = l8;
  }
}

// ================= embedding + relu -> split planes =================
__global__ void embed_relu_split_k(const float* __restrict__ emb, const int* __restrict__ tok,
                                   f16* __restrict__ xhi, f16* __restrict__ xlo) {
  int idx = blockIdx.x * 256 + threadIdx.x;      // 65536 = 256*1024/4
  int b = idx >> 8;
  int k4 = (idx & 255) << 2;
  float4 v = *(const float4*)(emb + (size_t)tok[b] * HD + k4);
  float vv[4] = {fmaxf(v.x, 0.0f), fmaxf(v.y, 0.0f), fmaxf(v.z, 0.0f), fmaxf(v.w, 0.0f)};
  f16x4 h4, l4;
  #pragma unroll
  for (int j = 0; j < 4; ++j) {
    f16 h = (f16)vv[j];
    h4[j] = h;
    l4[j] = (f16)(vv[j] - (float)h);
  }
  *(f16x4*)(xhi + (size_t)b * HD + k4) = h4;
  *(f16x4*)(xlo + (size_t)b * HD + k4) = l4;
}

// fallback embed (fp32 out) for tier B/C
__global__ void embed_relu_k(const float* __restrict__ emb, const int* __restrict__ tok,
                             float* __restrict__ x) {
  int idx = blockIdx.x * 256 + threadIdx.x;
  int b = idx >> 8;
  int k4 = (idx & 255) << 2;
  float4 v = *(const float4*)(emb + (size_t)tok[b] * HD + k4);
  v.x = fmaxf(v.x, 0.0f); v.y = fmaxf(v.y, 0.0f);
  v.z = fmaxf(v.z, 0.0f); v.w = fmaxf(v.w, 0.0f);
  *(float4*)(x + (size_t)b * HD + k4) = v;
}

// ================= GRU GEMM via split-f16 MFMA =================
// gg[b][0:3072] = x @ w_ih^T ; gg[b][3072:6144] = h @ w_hh^T   (fp32 accurate)
// tile 64(M) x 64(N), 4 waves (each 32x32), BK=32, K=1024. A register-direct, W via LDS.
__global__ __launch_bounds__(256)
void gemm_gru_mfma_k(const f16* __restrict__ a0_hi, const f16* __restrict__ a0_lo,
                     const f16* __restrict__ a1_hi, const f16* __restrict__ a1_lo,
                     const f16* __restrict__ wih_hi, const f16* __restrict__ wih_lo,
                     const f16* __restrict__ whh_hi, const f16* __restrict__ whh_lo,
                     float* __restrict__ gg) {
  __shared__ f16 lb_hi[2048];   // 64 N-rows x 32 k = 4 KB ; atom a = kg*64+n -> w[n][k0+kg*8..+8]
  __shared__ f16 lb_lo[2048];
  f16x8* lbv_hi = (f16x8*)lb_hi;
  f16x8* lbv_lo = (f16x8*)lb_lo;
  const int tid = threadIdx.x;
  const int lane = tid & 63;
  const int wave = tid >> 6;
  const int wm = wave >> 1, wn = wave & 1;
  const int l15 = lane & 15, l4 = lane >> 4;
  const int n0g = blockIdx.x * 64;   // 0..6080
  const int m0 = blockIdx.y * 64;    // 0..192

  const f16 *ahi, *alo, *whi, *wlo; int nc;
  if (n0g < 3072) { ahi = a0_hi; alo = a0_lo; whi = wih_hi; wlo = wih_lo; nc = n0g; }
  else            { ahi = a1_hi; alo = a1_lo; whi = whh_hi; wlo = whh_lo; nc = n0g - 3072; }

  f32x4 acc[2][2];
  #pragma unroll
  for (int mi = 0; mi < 2; ++mi)
    #pragma unroll
    for (int ni = 0; ni < 2; ++ni) acc[mi][ni] = (f32x4){0.f, 0.f, 0.f, 0.f};

  // stage one 4KB plane tile: 4 waves x 1 global_load_lds (64 lanes x 16B)
  #define GSTAGE(psrc, lbase, k0) { \
    int aidx = wave * 64 + lane; \
    int n = aidx & 63, kg = aidx >> 6; \
    const f16* src = psrc + (size_t)(nc + n) * HD + (k0) + kg * 8; \
    __builtin_amdgcn_global_load_lds((const GLOBAL_AS void*)src, \
        (LDS_AS void*)(lbase + wave * 512), 16, 0, 0); \
  }

  GSTAGE(whi, lb_hi, 0);
  GSTAGE(wlo, lb_lo, 0);
  __syncthreads();

  for (int kt = 0; kt < 32; ++kt) {
    const int k0 = kt * 32;
    f16x8 bh[2], bl[2], ah[2], al[2];
    #pragma unroll
    for (int ni = 0; ni < 2; ++ni) {
      int nl = wn * 32 + ni * 16 + l15;
      bh[ni] = lbv_hi[l4 * 64 + nl];
      bl[ni] = lbv_lo[l4 * 64 + nl];
    }
    #pragma unroll
    for (int mi = 0; mi < 2; ++mi) {
      size_t rowoff = (size_t)(m0 + wm * 32 + mi * 16 + l15) * HD + k0 + l4 * 8;
      ah[mi] = *(const f16x8*)(ahi + rowoff);
      al[mi] = *(const f16x8*)(alo + rowoff);
    }
    __syncthreads();                 // LDS reads of tile kt done
    if (kt < 31) {
      GSTAGE(whi, lb_hi, k0 + 32);
      GSTAGE(wlo, lb_lo, k0 + 32);
    }
    #pragma unroll
    for (int mi = 0; mi < 2; ++mi)
      #pragma unroll
      for (int ni = 0; ni < 2; ++ni) {
        acc[mi][ni] = __builtin_amdgcn_mfma_f32_16x16x32_f16(ah[mi], bh[ni], acc[mi][ni], 0, 0, 0);
        acc[mi][ni] = __builtin_amdgcn_mfma_f32_16x16x32_f16(ah[mi], bl[ni], acc[mi][ni], 0, 0, 0);
        acc[mi][ni] = __builtin_amdgcn_mfma_f32_16x16x32_f16(al[mi], bh[ni], acc[mi][ni], 0, 0, 0);
      }
    __syncthreads();                 // stage kt+1 complete
  }
  #undef GSTAGE

  #pragma unroll
  for (int mi = 0; mi < 2; ++mi)
    #pragma unroll
    for (int ni = 0; ni < 2; ++ni) {
      const int col = n0g + wn * 32 + ni * 16 + l15;
      #pragma unroll
      for (int r = 0; r < 4; ++r) {
        const int row = m0 + wm * 32 + mi * 16 + l4 * 4 + r;
        gg[(size_t)row * 6144 + col] = acc[mi][ni][r];
      }
    }
}

// ================= GRU gates (single partial) + split h output =================
__global__ void gru_gates_split_k(const float* __restrict__ gg,
                                  const float* __restrict__ b_ih, const float* __restrict__ b_hh,
                                  const float* __restrict__ h_old, float* __restrict__ h_new,
                                  f16* __restrict__ hhi, f16* __restrict__ hlo) {
  int idx = blockIdx.x * 256 + threadIdx.x;   // 65536
  int b = idx >> 8;
  int k4 = (idx & 255) << 2;
  const float* g = gg + (size_t)b * 6144;
  float4 gir = *(const float4*)(g + k4);
  float4 giz = *(const float4*)(g + 1024 + k4);
  float4 gin = *(const float4*)(g + 2048 + k4);
  float4 ghr = *(const float4*)(g + 3072 + k4);
  float4 ghz = *(const float4*)(g + 4096 + k4);
  float4 ghn = *(const float4*)(g + 5120 + k4);
  float4 bir = *(const float4*)(b_ih + k4);
  float4 biz = *(const float4*)(b_ih + 1024 + k4);
  float4 bin = *(const float4*)(b_ih + 2048 + k4);
  float4 bhr = *(const float4*)(b_hh + k4);
  float4 bhz = *(const float4*)(b_hh + 1024 + k4);
  float4 bhn = *(const float4*)(b_hh + 2048 + k4);
  float4 ho  = *(const float4*)(h_old + (size_t)b * HD + k4);
  float4 o;
  #define GATE(c) { \
    float rr = sigmoidf_(gir.c + bir.c + ghr.c + bhr.c); \
    float zz = sigmoidf_(giz.c + biz.c + ghz.c + bhz.c); \
    float nn = tanhf(gin.c + bin.c + rr * (ghn.c + bhn.c)); \
    o.c = (1.0f - zz) * nn + zz * ho.c; }
  GATE(x) GATE(y) GATE(z) GATE(w)
  #undef GATE
  *(float4*)(h_new + (size_t)b * HD + k4) = o;
  float vv[4] = {o.x, o.y, o.z, o.w};
  f16x4 h4, l4;
  #pragma unroll
  for (int j = 0; j < 4; ++j) {
    f16 h = (f16)vv[j];
    h4[j] = h;
    l4[j] = (f16)(vv[j] - (float)h);
  }
  *(f16x4*)(hhi + (size_t)b * HD + k4) = h4;
  *(f16x4*)(hlo + (size_t)b * HD + k4) = l4;
}

// ================= tier-B fp32 GRU GEMM (round-2) =================
__global__ __launch_bounds__(256)
void gemm_gru64_k(const float* __restrict__ x, const float* __restrict__ h,
                  const float* __restrict__ w_ih, const float* __restrict__ w_hh,
                  float* __restrict__ gg2) {
  __shared__ float sa[32][68];
  __shared__ float sw[32][68];
  const int tid = threadIdx.x;
  const int ty = tid >> 4, tx = tid & 15;
  const int lr = tid >> 3;
  const int lc = (tid & 7) << 2;
  const int n0g = blockIdx.x * 64;
  const int m0 = blockIdx.y * 64;
  const int kb = blockIdx.z * 512;
  const float* A; const float* W; int nc;
  if (n0g < 3072) { A = x; W = w_ih; nc = n0g; }
  else            { A = h; W = w_hh; nc = n0g - 3072; }
  float acc[4][4];
  #pragma unroll
  for (int i = 0; i < 4; ++i)
    #pragma unroll
    for (int j = 0; j < 4; ++j) acc[i][j] = 0.0f;
  for (int k0 = kb; k0 < kb + 512; k0 += 32) {
    #pragma unroll
    for (int p = 0; p < 2; ++p) {
      int row = lr + (p << 5);
      float4 va = *(const float4*)(A + (size_t)(m0 + row) * HD + k0 + lc);
      sa[lc + 0][row] = va.x; sa[lc + 1][row] = va.y;
      sa[lc + 2][row] = va.z; sa[lc + 3][row] = va.w;
      float4 vw = *(const float4*)(W + (size_t)(nc + row) * HD + k0 + lc);
      sw[lc + 0][row] = vw.x; sw[lc + 1][row] = vw.y;
      sw[lc + 2][row] = vw.z; sw[lc + 3][row] = vw.w;
    }
    __syncthreads();
    #pragma unroll
    for (int kk = 0; kk < 32; ++kk) {
      float4 a4 = *(const float4*)&sa[kk][ty << 2];
      float4 w4 = *(const float4*)&sw[kk][tx << 2];
      float av[4] = {a4.x, a4.y, a4.z, a4.w};
      float wv[4] = {w4.x, w4.y, w4.z, w4.w};
      #pragma unroll
      for (int i = 0; i < 4; ++i)
        #pragma unroll
        for (int j = 0; j < 4; ++j) acc[i][j] += av[i] * wv[j];
    }
    __syncthreads();
  }
  float* outp = gg2 + (size_t)blockIdx.z * NBATCH * 6144;
  #pragma unroll
  for (int i = 0; i < 4; ++i) {
    float4 r; r.x = acc[i][0]; r.y = acc[i][1]; r.z = acc[i][2]; r.w = acc[i][3];
    *(float4*)(outp + (size_t)(m0 + (ty << 2) + i) * 6144 + n0g + (tx << 2)) = r;
  }
}

static __device__ __forceinline__ float4 add4_(float4 a, float4 b) {
  float4 r; r.x = a.x + b.x; r.y = a.y + b.y; r.z = a.z + b.z; r.w = a.w + b.w; return r;
}
__global__ void gru_gates2_k(const float* __restrict__ gg2,
                             const float* __restrict__ b_ih, const float* __restrict__ b_hh,
                             const float* __restrict__ h_old, float* __restrict__ h_new) {
  int idx = blockIdx.x * 256 + threadIdx.x;
  int b = idx >> 8;
  int k4 = (idx & 255) << 2;
  const float* g0 = gg2 + (size_t)b * 6144;
  const float* g1 = gg2 + (size_t)NBATCH * 6144 + (size_t)b * 6144;
  #define LD2(off) add4_(*(const float4*)(g0 + (off) + k4), *(const float4*)(g1 + (off) + k4))
  float4 gir = LD2(0);
  float4 giz = LD2(1024);
  float4 gin = LD2(2048);
  float4 ghr = LD2(3072);
  float4 ghz = LD2(4096);
  float4 ghn = LD2(5120);
  #undef LD2
  float4 bir = *(const float4*)(b_ih + k4);
  float4 biz = *(const float4*)(b_ih + 1024 + k4);
  float4 bin = *(const float4*)(b_ih + 2048 + k4);
  float4 bhr = *(const float4*)(b_hh + k4);
  float4 bhz = *(const float4*)(b_hh + 1024 + k4);
  float4 bhn = *(const float4*)(b_hh + 2048 + k4);
  float4 ho  = *(const float4*)(h_old + (size_t)b * HD + k4);
  float4 o;
  #define GATE(c) { \
    float rr = sigmoidf_(gir.c + bir.c + ghr.c + bhr.c); \
    float zz = sigmoidf_(giz.c + biz.c + ghz.c + bhz.c); \
    float nn = tanhf(gin.c + bin.c + rr * (ghn.c + bhn.c)); \
    o.c = (1.0f - zz) * nn + zz * ho.c; }
  GATE(x) GATE(y) GATE(z) GATE(w)
  #undef GATE
  *(float4*)(h_new + (size_t)b * HD + k4) = o;
}

// ================= logits GEMM, f16 MFMA (round-2, validated) =================
__global__ __launch_bounds__(256)
void gemm_logits_f16_k(const f16* __restrict__ xf, const f16* __restrict__ wf,
                       const float* __restrict__ bias, float* __restrict__ out) {
  __shared__ f16 lb_raw[4096];
  f16x8* lbv = (f16x8*)lb_raw;
  const int tid = threadIdx.x;
  const int lane = tid & 63;
  const int wave = tid >> 6;
  const int wm = wave >> 1, wn = wave & 1;
  const int l15 = lane & 15, l4 = lane >> 4;
  const int n0 = blockIdx.x * 128;
  const int m0 = blockIdx.y * 128;

  f32x4 acc[4][4];
  #pragma unroll
  for (int mi = 0; mi < 4; ++mi)
    #pragma unroll
    for (int ni = 0; ni < 4; ++ni) acc[mi][ni] = (f32x4){0.f, 0.f, 0.f, 0.f};

  f16x8 a_cur[4], a_nxt[4];

  #define STAGE(k0) { \
    _Pragma("unroll") \
    for (int jj = 0; jj < 2; ++jj) { \
      int j = wave * 2 + jj; \
      int a = j * 64 + lane; \
      int n = a & 127, kg = a >> 7; \
      const f16* src = wf + (size_t)(n0 + n) * 1024 + (k0) + kg * 8; \
      __builtin_amdgcn_global_load_lds((const GLOBAL_AS void*)src, \
          (LDS_AS void*)(lb_raw + (size_t)j * 512), 16, 0, 0); \
    } }
  #define LOADA(k0, dst) { \
    _Pragma("unroll") \
    for (int mi = 0; mi < 4; ++mi) { \
      int row = m0 + wm * 64 + mi * 16 + l15; \
      dst[mi] = *(const f16x8*)(xf + (size_t)row * 1024 + (k0) + l4 * 8); \
    } }

  STAGE(0);
  LOADA(0, a_cur);
  __syncthreads();

  for (int kt = 0; kt < 32; ++kt) {
    f16x8 b[4];
    #pragma unroll
    for (int ni = 0; ni < 4; ++ni) {
      int nl = wn * 64 + ni * 16 + l15;
      b[ni] = lbv[l4 * 128 + nl];
    }
    if (kt < 31) LOADA((kt + 1) * 32, a_nxt);
    __syncthreads();
    if (kt < 31) STAGE((kt + 1) * 32);
    #pragma unroll
    for (int mi = 0; mi < 4; ++mi)
      #pragma unroll
      for (int ni = 0; ni < 4; ++ni)
        acc[mi][ni] = __builtin_amdgcn_mfma_f32_16x16x32_f16(a_cur[mi], b[ni], acc[mi][ni], 0, 0, 0);
    __syncthreads();
    #pragma unroll
    for (int mi = 0; mi < 4; ++mi) a_cur[mi] = a_nxt[mi];
  }
  #undef STAGE
  #undef LOADA

  #pragma unroll
  for (int mi = 0; mi < 4; ++mi)
    #pragma unroll
    for (int ni = 0; ni < 4; ++ni) {
      const int col = n0 + wn * 64 + ni * 16 + l15;
      const float bv = bias[col];
      #pragma unroll
      for (int r = 0; r < 4; ++r) {
        const int row = m0 + wm * 64 + mi * 16 + l4 * 4 + r;
        out[(size_t)row * OUT_ROW + col] = acc[mi][ni][r] + bv;
      }
    }
}

// ================= row reduce: approx max, lse, candidates =================
__global__ __launch_bounds__(256)
void row_reduce_cand_k(const float* __restrict__ lg, float* __restrict__ lse,
                       int* __restrict__ cand, int* __restrict__ cnt) {
  __shared__ float sv[256];
  __shared__ float ss[256];
  __shared__ int scnt;
  const int b = blockIdx.x;
  const int tid = threadIdx.x;
  const float* row = lg + (size_t)b * OUT_ROW;
  float vmax = -3.4e38f;
  for (int i = tid; i < VOC; i += 256) vmax = fmaxf(vmax, row[i]);
  sv[tid] = vmax;
  if (tid == 0) scnt = 0;
  __syncthreads();
  for (int off = 128; off; off >>= 1) {
    if (tid < off) sv[tid] = fmaxf(sv[tid], sv[tid + off]);
    __syncthreads();
  }
  float gmax = sv[0];
  float thr = gmax - 0.125f;
  float s = 0.0f;
  for (int i = tid; i < VOC; i += 256) {
    float v = row[i];
    s += expf(v - gmax);
    if (v >= thr) {
      int p = atomicAdd(&scnt, 1);
      if (p < 64) cand[b * 64 + p] = i;
    }
  }
  ss[tid] = s;
  __syncthreads();
  for (int off = 128; off; off >>= 1) {
    if (tid < off) ss[tid] += ss[tid + off];
    __syncthreads();
  }
  if (tid == 0) { lse[b] = gmax + logf(ss[0]); cnt[b] = scnt < 64 ? scnt : 64; }
}

// ================= exact argmax rescue =================
__global__ __launch_bounds__(256)
void rescue_k(const float* __restrict__ x, const float* __restrict__ w,
              const float* __restrict__ ob, const int* __restrict__ cand,
              const int* __restrict__ cnt, int* __restrict__ tok) {
  __shared__ double sd[256];
  __shared__ double s_best;
  __shared__ int s_bi;
  const int b = blockIdx.x;
  const int tid = threadIdx.x;
  const int c = cnt[b];
  if (tid == 0) { s_best = -1.0e300; s_bi = 0x7fffffff; }
  __syncthreads();
  for (int j = 0; j < c; ++j) {
    const int idx = cand[b * 64 + j];
    double p = 0.0;
    const float* xr = x + (size_t)b * HD;
    const float* wr = w + (size_t)idx * HD;
    for (int k = tid; k < HD; k += 256) p += (double)xr[k] * (double)wr[k];
    sd[tid] = p;
    __syncthreads();
    for (int off = 128; off; off >>= 1) {
      if (tid < off) sd[tid] += sd[tid + off];
      __syncthreads();
    }
    if (tid == 0) {
      double tot = sd[0] + (double)ob[idx];
      if (tot > s_best || (tot == s_best && idx < s_bi)) { s_best = tot; s_bi = idx; }
    }
    __syncthreads();
  }
  if (tid == 0) tok[b] = s_bi;
}

// ================= log_softmax fixup =================
__global__ void sub_lse_k(float* __restrict__ lg, const float* __restrict__ lse) {
  int idx = blockIdx.x * 256 + threadIdx.x;    // 2,048,000
  int b = idx / 8000;
  int r = idx - b * 8000;
  float l = lse[b];
  float4* p = (float4*)(lg + (size_t)b * OUT_ROW) + r;
  float4 v = *p;
  v.x -= l; v.y -= l; v.z -= l; v.w -= l;
  *p = v;
}

extern "C" void kernel_launch(void* const* d_in, const int* in_sizes, int n_in,
                              void* d_out, int out_size, void* d_ws, size_t ws_size,
                              hipStream_t stream) {
  (void)in_sizes; (void)n_in; (void)out_size;
  const float* enc_hidden = (const float*)d_in[1];   // [4,256,1024]
  const float* emb   = (const float*)d_in[2];        // [32000,1024]
  const float* w_ih  = (const float*)d_in[3];        // [4,3072,1024]
  const float* w_hh  = (const float*)d_in[4];        // [4,3072,1024]
  const float* b_ih  = (const float*)d_in[5];        // [4,3072]
  const float* b_hh  = (const float*)d_in[6];        // [4,3072]
  const float* out_w = (const float*)d_in[7];        // [32000,1024]
  const float* out_b = (const float*)d_in[8];        // [32000]
  float* out = (float*)d_out;

  size_t off = 0;
  char* base = (char*)d_ws;
  #define WSALLOC(bytes) ((void*)(base + off)); off += (((size_t)(bytes)) + 255) & ~(size_t)255
  float* hbuf  = (float*) WSALLOC(2 * 4 * BH * 4);          // 8.4 MB fp32 h, 2 parities
  float* gg2   = (float*) WSALLOC((size_t)2 * NBATCH * 6144 * 4);  // 12.6 MB
  float* xbuf  = (float*) WSALLOC(BH * 4);                  // fp32 x (tier B)
  f16*   xf16  = (f16*)   WSALLOC(BH * 2);                  // tier B logits A
  f16*   xs_hi = (f16*)   WSALLOC(BH * 2);
  f16*   xs_lo = (f16*)   WSALLOC(BH * 2);
  int*   tok   = (int*)   WSALLOC(1024);
  float* lse   = (float*) WSALLOC(1024);
  int*   cand  = (int*)   WSALLOC((size_t)NBATCH * 64 * 4);
  int*   cnt   = (int*)   WSALLOC(1024);
  f16*   wf16  = (f16*)   WSALLOC((size_t)VOC * HD * 2);    // 65.5 MB
  const size_t needB = off;
  f16*   hs_hi = (f16*)   WSALLOC(2 * 4 * BH * 2);          // 4.2 MB
  f16*   hs_lo = (f16*)   WSALLOC(2 * 4 * BH * 2);
  f16*   wih_hi = (f16*)  WSALLOC((size_t)4 * 3072 * HD * 2);  // 25.2 MB
  f16*   wih_lo = (f16*)  WSALLOC((size_t)4 * 3072 * HD * 2);
  f16*   whh_hi = (f16*)  WSALLOC((size_t)4 * 3072 * HD * 2);
  f16*   whh_lo = (f16*)  WSALLOC((size_t)4 * 3072 * HD * 2);
  const size_t needA = off;
  #undef WSALLOC
  const bool tierA = (needA <= ws_size);
  const bool tierB = !tierA && (needB <= ws_size);

  const size_t HSZ = 4 * BH;   // floats per parity buffer

  hipMemcpyAsync(hbuf, enc_hidden, HSZ * 4, hipMemcpyDeviceToDevice, stream);
  hipMemsetAsync(tok, 0, NBATCH * 4, stream);

  if (tierA) {
    // one-time conversions
    f32_to_f16_k<<<2048, 256, 0, stream>>>(out_w, wf16, (long)VOC * HD / 8);
    split_f32_k<<<2048, 256, 0, stream>>>(w_ih, wih_hi, wih_lo, (long)4 * 3072 * HD / 8);
    split_f32_k<<<2048, 256, 0, stream>>>(w_hh, whh_hi, whh_lo, (long)4 * 3072 * HD / 8);
    split_f32_k<<<512, 256, 0, stream>>>(enc_hidden, hs_hi, hs_lo, (long)4 * BH / 8);  // parity 0

    int p = 0;
    for (int t = 0; t < TSTEPS; ++t) {
      float* hp = hbuf + (size_t)p * HSZ;
      float* hn = hbuf + (size_t)(1 - p) * HSZ;
      f16* hp_hi = hs_hi + (size_t)p * 4 * BH;
      f16* hp_lo = hs_lo + (size_t)p * 4 * BH;
      f16* hn_hi = hs_hi + (size_t)(1 - p) * 4 * BH;
      f16* hn_lo = hs_lo + (size_t)(1 - p) * 4 * BH;

      embed_relu_split_k<<<256, 256, 0, stream>>>(emb, tok, xs_hi, xs_lo);

      for (int l = 0; l < 4; ++l) {
        const f16* a0hi = (l == 0) ? xs_hi : hn_hi + (size_t)(l - 1) * BH;
        const f16* a0lo = (l == 0) ? xs_lo : hn_lo + (size_t)(l - 1) * BH;
        gemm_gru_mfma_k<<<dim3(96, 4), 256, 0, stream>>>(
            a0hi, a0lo, hp_hi + (size_t)l * BH, hp_lo + (size_t)l * BH,
            wih_hi + (size_t)l * 3072 * HD, wih_lo + (size_t)l * 3072 * HD,
            whh_hi + (size_t)l * 3072 * HD, whh_lo + (size_t)l * 3072 * HD, gg2);
        gru_gates_split_k<<<256, 256, 0, stream>>>(
            gg2, b_ih + l * 3072, b_hh + l * 3072,
            hp + (size_t)l * BH, hn + (size_t)l * BH,
            hn_hi + (size_t)l * BH, hn_lo + (size_t)l * BH);
      }

      const float* lin = hn + (size_t)3 * BH;
      float* lg = out + (size_t)t * VOC;
      gemm_logits_f16_k<<<dim3(250, 2), 256, 0, stream>>>(hn_hi + (size_t)3 * BH, wf16, out_b, lg);
      row_reduce_cand_k<<<NBATCH, 256, 0, stream>>>(lg, lse, cand, cnt);
      rescue_k<<<NBATCH, 256, 0, stream>>>(lin, out_w, out_b, cand, cnt, tok);
      sub_lse_k<<<8000, 256, 0, stream>>>(lg, lse);

      p ^= 1;
    }
  } else if (tierB) {
    f32_to_f16_k<<<2048, 256, 0, stream>>>(out_w, wf16, (long)VOC * HD / 8);
    int p = 0;
    for (int t = 0; t < TSTEPS; ++t) {
      float* hp = hbuf + (size_t)p * HSZ;
      float* hn = hbuf + (size_t)(1 - p) * HSZ;
      embed_relu_k<<<256, 256, 0, stream>>>(emb, tok, xbuf);
      const float* lin = xbuf;
      for (int l = 0; l < 4; ++l) {
        gemm_gru64_k<<<dim3(96, 4, 2), 256, 0, stream>>>(
            lin, hp + (size_t)l * BH,
            w_ih + (size_t)l * 3072 * HD, w_hh + (size_t)l * 3072 * HD, gg2);
        gru_gates2_k<<<256, 256, 0, stream>>>(
            gg2, b_ih + l * 3072, b_hh + l * 3072,
            hp + (size_t)l * BH, hn + (size_t)l * BH);
        lin = hn + (size_t)l * BH;
      }
      float* lg = out + (size_t)t * VOC;
      f32_to_f16_k<<<128, 256, 0, stream>>>(lin, xf16, (long)BH / 8);
      gemm_logits_f16_k<<<dim3(250, 2), 256, 0, stream>>>(xf16, wf16, out_b, lg);
      row_reduce_cand_k<<<NBATCH, 256, 0, stream>>>(lg, lse, cand, cnt);
      rescue_k<<<NBATCH, 256, 0, stream>>>(lin, out_w, out_b, cand, cnt, tok);
      sub_lse_k<<<8000, 256, 0, stream>>>(lg, lse);
      p ^= 1;
    }
  }

  hipMemcpyAsync(out + (size_t)NBATCH * TSTEPS * VOC, hbuf, HSZ * 4,
                 hipMemcpyDeviceToDevice, stream);
}

// Round 5
// 8520.768 us; speedup vs baseline: 1.4878x; 1.0004x over previous
//
#include <hip/hip_runtime.h>
#include <math.h>

#define HD 1024
#define NBATCH 256
#define VOC 32000
#define TSTEPS 20
#define OUT_ROW 640000LL   // 20*32000, row stride (floats) between b rows in d_out
#define BH ((size_t)NBATCH * HD)

typedef _Float16 f16;
typedef __attribute__((ext_vector_type(4))) _Float16 f16x4;
typedef __attribute__((ext_vector_type(8))) _Float16 f16x8;
typedef __attribute__((ext_vector_type(4))) float f32x4;

#define GLOBAL_AS __attribute__((address_space(1)))
#define LDS_AS    __attribute__((address_space(3)))

static __device__ __forceinline__ float sigmoidf_(float v) {
  return 1.0f / (1.0f + expf(-v));
}

// ================= conversion kernels =================

// fp32 -> f16 (8 elems/thread, grid-stride)
__global__ void f32_to_f16_k(const float* __restrict__ in, f16* __restrict__ out, long n8) {
  long i = (long)blockIdx.x * 256 + threadIdx.x;
  long stride = (long)gridDim.x * 256;
  for (; i < n8; i += stride) {
    float4 a = *((const float4*)in + i * 2);
    float4 b = *((const float4*)in + i * 2 + 1);
    f16x8 o;
    o[0] = (f16)a.x; o[1] = (f16)a.y; o[2] = (f16)a.z; o[3] = (f16)a.w;
    o[4] = (f16)b.x; o[5] = (f16)b.y; o[6] = (f16)b.z; o[7] = (f16)b.w;
    *((f16x8*)out + i) = o;
  }
}

// fp32 -> split f16 (hi = f16(v), lo = f16(v - hi)), 8 elems/thread
__global__ void split_f32_k(const float* __restrict__ in, f16* __restrict__ hi,
                            f16* __restrict__ lo, long n8) {
  long i = (long)blockIdx.x * 256 + threadIdx.x;
  long stride = (long)gridDim.x * 256;
  for (; i < n8; i += stride) {
    float4 a = *((const float4*)in + i * 2);
    float4 b = *((const float4*)in + i * 2 + 1);
    float v[8] = {a.x, a.y, a.z, a.w, b.x, b.y, b.z, b.w};
    f16x8 h8, l8;
    #pragma unroll
    for (int j = 0; j < 8; ++j) {
      f16 h = (f16)v[j];
      h8[j] = h;
      l8[j] = (f16)(v[j] - (float)h);
    }
    *((f16x8*)hi + i) = h8;
    *((f16x8*)lo + i) = l8;
  }
}

// ================= embedding + relu -> split planes =================
__global__ void embed_relu_split_k(const float* __restrict__ emb, const int* __restrict__ tok,
                                   f16* __restrict__ xhi, f16* __restrict__ xlo) {
  int idx = blockIdx.x * 256 + threadIdx.x;      // 65536 = 256*1024/4
  int b = idx >> 8;
  int k4 = (idx & 255) << 2;
  float4 v = *(const float4*)(emb + (size_t)tok[b] * HD + k4);
  float vv[4] = {fmaxf(v.x, 0.0f), fmaxf(v.y, 0.0f), fmaxf(v.z, 0.0f), fmaxf(v.w, 0.0f)};
  f16x4 h4, l4;
  #pragma unroll
  for (int j = 0; j < 4; ++j) {
    f16 h = (f16)vv[j];
    h4[j] = h;
    l4[j] = (f16)(vv[j] - (float)h);
  }
  *(f16x4*)(xhi + (size_t)b * HD + k4) = h4;
  *(f16x4*)(xlo + (size_t)b * HD + k4) = l4;
}

// ================= GRU GEMM: split-f16 MFMA, fp32 weights split in-register =================
// gg2[z][b][0:3072] = x @ w_ih^T (K-half z) ; gg2[z][b][3072:6144] = h @ w_hh^T
// tile 64(M) x 64(N), 4 waves (each 32x32), K-split x2, BK=32. No LDS, no barriers.
__global__ __launch_bounds__(256)
void gemm_gru_mfma2_k(const f16* __restrict__ a0_hi, const f16* __restrict__ a0_lo,
                      const f16* __restrict__ a1_hi, const f16* __restrict__ a1_lo,
                      const float* __restrict__ w_ih, const float* __restrict__ w_hh,
                      float* __restrict__ gg2) {
  const int tid = threadIdx.x;
  const int lane = tid & 63;
  const int wave = tid >> 6;
  const int wm = wave >> 1, wn = wave & 1;
  const int l15 = lane & 15, l4 = lane >> 4;
  const int n0g = blockIdx.x * 64;   // 0..6080
  const int m0 = blockIdx.y * 64;    // 0..192
  const int kb = blockIdx.z * 512;   // K-half

  const f16 *ahi, *alo; const float* W; int nc;
  if (n0g < 3072) { ahi = a0_hi; alo = a0_lo; W = w_ih; nc = n0g; }
  else            { ahi = a1_hi; alo = a1_lo; W = w_hh; nc = n0g - 3072; }

  f32x4 acc[2][2];
  #pragma unroll
  for (int mi = 0; mi < 2; ++mi)
    #pragma unroll
    for (int ni = 0; ni < 2; ++ni) acc[mi][ni] = (f32x4){0.f, 0.f, 0.f, 0.f};

  // per-lane base pointers (fragment k index = l4*8 + j)
  const float* wp0 = W + (size_t)(nc + wn * 32 + l15) * HD + kb + l4 * 8;
  const float* wp1 = wp0 + (size_t)16 * HD;
  const f16* ah0 = ahi + (size_t)(m0 + wm * 32 + l15) * HD + kb + l4 * 8;
  const f16* ah1 = ah0 + (size_t)16 * HD;
  const f16* al0 = alo + (size_t)(m0 + wm * 32 + l15) * HD + kb + l4 * 8;
  const f16* al1 = al0 + (size_t)16 * HD;

  for (int kk = 0; kk < 512; kk += 32) {
    f16x8 ah[2], al[2], bh[2], bl[2];
    ah[0] = *(const f16x8*)(ah0 + kk);
    ah[1] = *(const f16x8*)(ah1 + kk);
    al[0] = *(const f16x8*)(al0 + kk);
    al[1] = *(const f16x8*)(al1 + kk);
    #pragma unroll
    for (int ni = 0; ni < 2; ++ni) {
      const float* wp = ni ? wp1 : wp0;
      float4 w0 = *(const float4*)(wp + kk);
      float4 w1 = *(const float4*)(wp + kk + 4);
      float wv[8] = {w0.x, w0.y, w0.z, w0.w, w1.x, w1.y, w1.z, w1.w};
      #pragma unroll
      for (int j = 0; j < 8; ++j) {
        f16 h = (f16)wv[j];
        bh[ni][j] = h;
        bl[ni][j] = (f16)(wv[j] - (float)h);
      }
    }
    #pragma unroll
    for (int mi = 0; mi < 2; ++mi)
      #pragma unroll
      for (int ni = 0; ni < 2; ++ni) {
        acc[mi][ni] = __builtin_amdgcn_mfma_f32_16x16x32_f16(ah[mi], bh[ni], acc[mi][ni], 0, 0, 0);
        acc[mi][ni] = __builtin_amdgcn_mfma_f32_16x16x32_f16(ah[mi], bl[ni], acc[mi][ni], 0, 0, 0);
        acc[mi][ni] = __builtin_amdgcn_mfma_f32_16x16x32_f16(al[mi], bh[ni], acc[mi][ni], 0, 0, 0);
      }
  }

  float* outp = gg2 + (size_t)blockIdx.z * NBATCH * 6144;
  #pragma unroll
  for (int mi = 0; mi < 2; ++mi)
    #pragma unroll
    for (int ni = 0; ni < 2; ++ni) {
      const int col = n0g + wn * 32 + ni * 16 + l15;
      #pragma unroll
      for (int r = 0; r < 4; ++r) {
        const int row = m0 + wm * 32 + mi * 16 + l4 * 4 + r;
        outp[(size_t)row * 6144 + col] = acc[mi][ni][r];
      }
    }
}

// ================= GRU gates over K-split partials; h carried as (hi,lo) =================
static __device__ __forceinline__ float4 add4_(float4 a, float4 b) {
  float4 r; r.x = a.x + b.x; r.y = a.y + b.y; r.z = a.z + b.z; r.w = a.w + b.w; return r;
}
__global__ void gru_gates_split2_k(const float* __restrict__ gg2,
                                   const float* __restrict__ b_ih, const float* __restrict__ b_hh,
                                   const f16* __restrict__ hold_hi, const f16* __restrict__ hold_lo,
                                   f16* __restrict__ hnew_hi, f16* __restrict__ hnew_lo) {
  int idx = blockIdx.x * 256 + threadIdx.x;   // 65536
  int b = idx >> 8;
  int k4 = (idx & 255) << 2;
  const float* g0 = gg2 + (size_t)b * 6144;
  const float* g1 = gg2 + (size_t)NBATCH * 6144 + (size_t)b * 6144;
  #define LD2(off) add4_(*(const float4*)(g0 + (off) + k4), *(const float4*)(g1 + (off) + k4))
  float4 gir = LD2(0);
  float4 giz = LD2(1024);
  float4 gin = LD2(2048);
  float4 ghr = LD2(3072);
  float4 ghz = LD2(4096);
  float4 ghn = LD2(5120);
  #undef LD2
  float4 bir = *(const float4*)(b_ih + k4);
  float4 biz = *(const float4*)(b_ih + 1024 + k4);
  float4 bin = *(const float4*)(b_ih + 2048 + k4);
  float4 bhr = *(const float4*)(b_hh + k4);
  float4 bhz = *(const float4*)(b_hh + 1024 + k4);
  float4 bhn = *(const float4*)(b_hh + 2048 + k4);
  f16x4 hh = *(const f16x4*)(hold_hi + (size_t)b * HD + k4);
  f16x4 hl = *(const f16x4*)(hold_lo + (size_t)b * HD + k4);
  float hov[4];
  #pragma unroll
  for (int j = 0; j < 4; ++j) hov[j] = (float)hh[j] + (float)hl[j];
  float4 ho; ho.x = hov[0]; ho.y = hov[1]; ho.z = hov[2]; ho.w = hov[3];
  float4 o;
  #define GATE(c) { \
    float rr = sigmoidf_(gir.c + bir.c + ghr.c + bhr.c); \
    float zz = sigmoidf_(giz.c + biz.c + ghz.c + bhz.c); \
    float nn = tanhf(gin.c + bin.c + rr * (ghn.c + bhn.c)); \
    o.c = (1.0f - zz) * nn + zz * ho.c; }
  GATE(x) GATE(y) GATE(z) GATE(w)
  #undef GATE
  float vv[4] = {o.x, o.y, o.z, o.w};
  f16x4 h4, l4;
  #pragma unroll
  for (int j = 0; j < 4; ++j) {
    f16 h = (f16)vv[j];
    h4[j] = h;
    l4[j] = (f16)(vv[j] - (float)h);
  }
  *(f16x4*)(hnew_hi + (size_t)b * HD + k4) = h4;
  *(f16x4*)(hnew_lo + (size_t)b * HD + k4) = l4;
}

// ================= logits GEMM, f16 MFMA (round-2, validated) =================
__global__ __launch_bounds__(256)
void gemm_logits_f16_k(const f16* __restrict__ xf, const f16* __restrict__ wf,
                       const float* __restrict__ bias, float* __restrict__ out) {
  __shared__ f16 lb_raw[4096];
  f16x8* lbv = (f16x8*)lb_raw;
  const int tid = threadIdx.x;
  const int lane = tid & 63;
  const int wave = tid >> 6;
  const int wm = wave >> 1, wn = wave & 1;
  const int l15 = lane & 15, l4 = lane >> 4;
  const int n0 = blockIdx.x * 128;
  const int m0 = blockIdx.y * 128;

  f32x4 acc[4][4];
  #pragma unroll
  for (int mi = 0; mi < 4; ++mi)
    #pragma unroll
    for (int ni = 0; ni < 4; ++ni) acc[mi][ni] = (f32x4){0.f, 0.f, 0.f, 0.f};

  f16x8 a_cur[4], a_nxt[4];

  #define STAGE(k0) { \
    _Pragma("unroll") \
    for (int jj = 0; jj < 2; ++jj) { \
      int j = wave * 2 + jj; \
      int a = j * 64 + lane; \
      int n = a & 127, kg = a >> 7; \
      const f16* src = wf + (size_t)(n0 + n) * 1024 + (k0) + kg * 8; \
      __builtin_amdgcn_global_load_lds((const GLOBAL_AS void*)src, \
          (LDS_AS void*)(lb_raw + (size_t)j * 512), 16, 0, 0); \
    } }
  #define LOADA(k0, dst) { \
    _Pragma("unroll") \
    for (int mi = 0; mi < 4; ++mi) { \
      int row = m0 + wm * 64 + mi * 16 + l15; \
      dst[mi] = *(const f16x8*)(xf + (size_t)row * 1024 + (k0) + l4 * 8); \
    } }

  STAGE(0);
  LOADA(0, a_cur);
  __syncthreads();

  for (int kt = 0; kt < 32; ++kt) {
    f16x8 b[4];
    #pragma unroll
    for (int ni = 0; ni < 4; ++ni) {
      int nl = wn * 64 + ni * 16 + l15;
      b[ni] = lbv[l4 * 128 + nl];
    }
    if (kt < 31) LOADA((kt + 1) * 32, a_nxt);
    __syncthreads();
    if (kt < 31) STAGE((kt + 1) * 32);
    #pragma unroll
    for (int mi = 0; mi < 4; ++mi)
      #pragma unroll
      for (int ni = 0; ni < 4; ++ni)
        acc[mi][ni] = __builtin_amdgcn_mfma_f32_16x16x32_f16(a_cur[mi], b[ni], acc[mi][ni], 0, 0, 0);
    __syncthreads();
    #pragma unroll
    for (int mi = 0; mi < 4; ++mi) a_cur[mi] = a_nxt[mi];
  }
  #undef STAGE
  #undef LOADA

  #pragma unroll
  for (int mi = 0; mi < 4; ++mi)
    #pragma unroll
    for (int ni = 0; ni < 4; ++ni) {
      const int col = n0 + wn * 64 + ni * 16 + l15;
      const float bv = bias[col];
      #pragma unroll
      for (int r = 0; r < 4; ++r) {
        const int row = m0 + wm * 64 + mi * 16 + l4 * 4 + r;
        out[(size_t)row * OUT_ROW + col] = acc[mi][ni][r] + bv;
      }
    }
}

// ================= row reduce: approx max, lse, candidates =================
__global__ __launch_bounds__(256)
void row_reduce_cand_k(const float* __restrict__ lg, float* __restrict__ lse,
                       int* __restrict__ cand, int* __restrict__ cnt) {
  __shared__ float sv[256];
  __shared__ float ss[256];
  __shared__ int scnt;
  const int b = blockIdx.x;
  const int tid = threadIdx.x;
  const float* row = lg + (size_t)b * OUT_ROW;
  float vmax = -3.4e38f;
  for (int i = tid; i < VOC; i += 256) vmax = fmaxf(vmax, row[i]);
  sv[tid] = vmax;
  if (tid == 0) scnt = 0;
  __syncthreads();
  for (int off = 128; off; off >>= 1) {
    if (tid < off) sv[tid] = fmaxf(sv[tid], sv[tid + off]);
    __syncthreads();
  }
  float gmax = sv[0];
  float thr = gmax - 0.125f;
  float s = 0.0f;
  for (int i = tid; i < VOC; i += 256) {
    float v = row[i];
    s += expf(v - gmax);
    if (v >= thr) {
      int p = atomicAdd(&scnt, 1);
      if (p < 64) cand[b * 64 + p] = i;
    }
  }
  ss[tid] = s;
  __syncthreads();
  for (int off = 128; off; off >>= 1) {
    if (tid < off) ss[tid] += ss[tid + off];
    __syncthreads();
  }
  if (tid == 0) { lse[b] = gmax + logf(ss[0]); cnt[b] = scnt < 64 ? scnt : 64; }
}

// ================= exact argmax rescue (x reconstructed from split) =================
__global__ __launch_bounds__(256)
void rescue_split_k(const f16* __restrict__ xhi, const f16* __restrict__ xlo,
                    const float* __restrict__ w, const float* __restrict__ ob,
                    const int* __restrict__ cand, const int* __restrict__ cnt,
                    int* __restrict__ tok) {
  __shared__ double sd[256];
  __shared__ double s_best;
  __shared__ int s_bi;
  const int b = blockIdx.x;
  const int tid = threadIdx.x;
  const int c = cnt[b];
  if (tid == 0) { s_best = -1.0e300; s_bi = 0; }
  __syncthreads();
  for (int j = 0; j < c; ++j) {
    const int idx = cand[b * 64 + j];
    double p = 0.0;
    const f16* xh = xhi + (size_t)b * HD;
    const f16* xl = xlo + (size_t)b * HD;
    const float* wr = w + (size_t)idx * HD;
    for (int k = tid; k < HD; k += 256)
      p += ((double)xh[k] + (double)xl[k]) * (double)wr[k];
    sd[tid] = p;
    __syncthreads();
    for (int off = 128; off; off >>= 1) {
      if (tid < off) sd[tid] += sd[tid + off];
      __syncthreads();
    }
    if (tid == 0) {
      double tot = sd[0] + (double)ob[idx];
      if (j == 0 || tot > s_best || (tot == s_best && idx < s_bi)) { s_best = tot; s_bi = idx; }
    }
    __syncthreads();
  }
  if (tid == 0) tok[b] = s_bi;
}

// ================= log_softmax fixup =================
__global__ void sub_lse_k(float* __restrict__ lg, const float* __restrict__ lse) {
  int idx = blockIdx.x * 256 + threadIdx.x;    // 2,048,000
  int b = idx / 8000;
  int r = idx - b * 8000;
  float l = lse[b];
  float4* p = (float4*)(lg + (size_t)b * OUT_ROW) + r;
  float4 v = *p;
  v.x -= l; v.y -= l; v.z -= l; v.w -= l;
  *p = v;
}

// ================= final h output: out = hi + lo =================
__global__ void combine_h_k(const f16* __restrict__ hi, const f16* __restrict__ lo,
                            float* __restrict__ o, int n4) {
  int i = blockIdx.x * 256 + threadIdx.x;   // n4 = 4*BH/4 = 262,144 float4 chunks
  if (i >= n4) return;
  f16x4 h = ((const f16x4*)hi)[i];
  f16x4 l = ((const f16x4*)lo)[i];
  float4 v;
  v.x = (float)h[0] + (float)l[0];
  v.y = (float)h[1] + (float)l[1];
  v.z = (float)h[2] + (float)l[2];
  v.w = (float)h[3] + (float)l[3];
  ((float4*)o)[i] = v;
}

extern "C" void kernel_launch(void* const* d_in, const int* in_sizes, int n_in,
                              void* d_out, int out_size, void* d_ws, size_t ws_size,
                              hipStream_t stream) {
  (void)in_sizes; (void)n_in; (void)out_size;
  const float* enc_hidden = (const float*)d_in[1];   // [4,256,1024]
  const float* emb   = (const float*)d_in[2];        // [32000,1024]
  const float* w_ih  = (const float*)d_in[3];        // [4,3072,1024]
  const float* w_hh  = (const float*)d_in[4];        // [4,3072,1024]
  const float* b_ih  = (const float*)d_in[5];        // [4,3072]
  const float* b_hh  = (const float*)d_in[6];        // [4,3072]
  const float* out_w = (const float*)d_in[7];        // [32000,1024]
  const float* out_b = (const float*)d_in[8];        // [32000]
  float* out = (float*)d_out;

  size_t off = 0;
  char* base = (char*)d_ws;
  #define WSALLOC(bytes) ((void*)(base + off)); off += (((size_t)(bytes)) + 255) & ~(size_t)255
  float* gg2   = (float*) WSALLOC((size_t)2 * NBATCH * 6144 * 4);  // 12.6 MB (K-split x2)
  f16*   hs_hi = (f16*)   WSALLOC(2 * 4 * BH * 2);                 // 4.2 MB (2 parities)
  f16*   hs_lo = (f16*)   WSALLOC(2 * 4 * BH * 2);                 // 4.2 MB
  f16*   xs_hi = (f16*)   WSALLOC(BH * 2);                         // 0.5 MB
  f16*   xs_lo = (f16*)   WSALLOC(BH * 2);                         // 0.5 MB
  int*   tok   = (int*)   WSALLOC(1024);
  float* lse   = (float*) WSALLOC(1024);
  int*   cand  = (int*)   WSALLOC((size_t)NBATCH * 64 * 4);
  int*   cnt   = (int*)   WSALLOC(1024);
  f16*   wf16  = (f16*)   WSALLOC((size_t)VOC * HD * 2);           // 65.5 MB
  #undef WSALLOC
  // total ~87.6 MB <= 88.1 MB proven available (round-2 f16path ran)
  if (off > ws_size) return;   // fail loudly (poisoned output) rather than corrupt

  // one-time conversions
  f32_to_f16_k<<<2048, 256, 0, stream>>>(out_w, wf16, (long)VOC * HD / 8);
  split_f32_k<<<512, 256, 0, stream>>>(enc_hidden, hs_hi, hs_lo, (long)(4 * BH / 8));  // parity 0
  hipMemsetAsync(tok, 0, NBATCH * 4, stream);

  int p = 0;
  for (int t = 0; t < TSTEPS; ++t) {
    f16* hp_hi = hs_hi + (size_t)p * 4 * BH;
    f16* hp_lo = hs_lo + (size_t)p * 4 * BH;
    f16* hn_hi = hs_hi + (size_t)(1 - p) * 4 * BH;
    f16* hn_lo = hs_lo + (size_t)(1 - p) * 4 * BH;

    embed_relu_split_k<<<256, 256, 0, stream>>>(emb, tok, xs_hi, xs_lo);

    for (int l = 0; l < 4; ++l) {
      const f16* a0hi = (l == 0) ? xs_hi : hn_hi + (size_t)(l - 1) * BH;
      const f16* a0lo = (l == 0) ? xs_lo : hn_lo + (size_t)(l - 1) * BH;
      gemm_gru_mfma2_k<<<dim3(96, 4, 2), 256, 0, stream>>>(
          a0hi, a0lo, hp_hi + (size_t)l * BH, hp_lo + (size_t)l * BH,
          w_ih + (size_t)l * 3072 * HD, w_hh + (size_t)l * 3072 * HD, gg2);
      gru_gates_split2_k<<<256, 256, 0, stream>>>(
          gg2, b_ih + l * 3072, b_hh + l * 3072,
          hp_hi + (size_t)l * BH, hp_lo + (size_t)l * BH,
          hn_hi + (size_t)l * BH, hn_lo + (size_t)l * BH);
    }

    float* lg = out + (size_t)t * VOC;
    gemm_logits_f16_k<<<dim3(250, 2), 256, 0, stream>>>(hn_hi + (size_t)3 * BH, wf16, out_b, lg);
    row_reduce_cand_k<<<NBATCH, 256, 0, stream>>>(lg, lse, cand, cnt);
    rescue_split_k<<<NBATCH, 256, 0, stream>>>(hn_hi + (size_t)3 * BH, hn_lo + (size_t)3 * BH,
                                               out_w, out_b, cand, cnt, tok);
    sub_lse_k<<<8000, 256, 0, stream>>>(lg, lse);

    p ^= 1;
  }

  // after 20 steps the final h splits sit in parity 0; 4*BH floats = 262,144 float4
  combine_h_k<<<1024, 256, 0, stream>>>(hs_hi, hs_lo,
                                        out + (size_t)NBATCH * TSTEPS * VOC,
                                        (int)(4 * BH / 4));
}

// Round 6
// 6237.995 us; speedup vs baseline: 2.0323x; 1.3659x over previous
//
#include <hip/hip_runtime.h>
#include <math.h>

#define HD 1024
#define NBATCH 256
#define VOC 32000
#define TSTEPS 20
#define OUT_ROW 640000LL   // 20*32000, row stride (floats) between b rows in d_out
#define BH ((size_t)NBATCH * HD)

typedef _Float16 f16;
typedef __attribute__((ext_vector_type(4))) _Float16 f16x4;
typedef __attribute__((ext_vector_type(8))) _Float16 f16x8;
typedef __attribute__((ext_vector_type(4))) float f32x4;

#define GLOBAL_AS __attribute__((address_space(1)))
#define LDS_AS    __attribute__((address_space(3)))

static __device__ __forceinline__ float sigmoidf_(float v) {
  return 1.0f / (1.0f + expf(-v));
}

// ================= conversion kernels =================

__global__ void f32_to_f16_k(const float* __restrict__ in, f16* __restrict__ out, long n8) {
  long i = (long)blockIdx.x * 256 + threadIdx.x;
  long stride = (long)gridDim.x * 256;
  for (; i < n8; i += stride) {
    float4 a = *((const float4*)in + i * 2);
    float4 b = *((const float4*)in + i * 2 + 1);
    f16x8 o;
    o[0] = (f16)a.x; o[1] = (f16)a.y; o[2] = (f16)a.z; o[3] = (f16)a.w;
    o[4] = (f16)b.x; o[5] = (f16)b.y; o[6] = (f16)b.z; o[7] = (f16)b.w;
    *((f16x8*)out + i) = o;
  }
}

__global__ void split_f32_k(const float* __restrict__ in, f16* __restrict__ hi,
                            f16* __restrict__ lo, long n8) {
  long i = (long)blockIdx.x * 256 + threadIdx.x;
  long stride = (long)gridDim.x * 256;
  for (; i < n8; i += stride) {
    float4 a = *((const float4*)in + i * 2);
    float4 b = *((const float4*)in + i * 2 + 1);
    float v[8] = {a.x, a.y, a.z, a.w, b.x, b.y, b.z, b.w};
    f16x8 h8, l8;
    #pragma unroll
    for (int j = 0; j < 8; ++j) {
      f16 h = (f16)v[j];
      h8[j] = h;
      l8[j] = (f16)(v[j] - (float)h);
    }
    *((f16x8*)hi + i) = h8;
    *((f16x8*)lo + i) = l8;
  }
}

// ================= embedding + relu -> split planes =================
__global__ void embed_relu_split_k(const float* __restrict__ emb, const int* __restrict__ tok,
                                   f16* __restrict__ xhi, f16* __restrict__ xlo) {
  int idx = blockIdx.x * 256 + threadIdx.x;      // 65536 = 256*1024/4
  int b = idx >> 8;
  int k4 = (idx & 255) << 2;
  float4 v = *(const float4*)(emb + (size_t)tok[b] * HD + k4);
  float vv[4] = {fmaxf(v.x, 0.0f), fmaxf(v.y, 0.0f), fmaxf(v.z, 0.0f), fmaxf(v.w, 0.0f)};
  f16x4 h4, l4;
  #pragma unroll
  for (int j = 0; j < 4; ++j) {
    f16 h = (f16)vv[j];
    h4[j] = h;
    l4[j] = (f16)(vv[j] - (float)h);
  }
  *(f16x4*)(xhi + (size_t)b * HD + k4) = h4;
  *(f16x4*)(xlo + (size_t)b * HD + k4) = l4;
}

// ================= GRU GEMM v3: LDS-staged split-f16 MFMA =================
// Stage fp32 W coalesced (full 128B lines) -> split hi/lo in regs -> LDS atoms;
// A hi/lo planes staged the same way. MFMA reads conflict-free ds_read_b128.
// tile 64(M) x 64(N), 4 waves (2x2 of 32x32), K-split x2 (z), BK=32.
__global__ __launch_bounds__(256)
void gemm_gru_mfma3_k(const f16* __restrict__ a0_hi, const f16* __restrict__ a0_lo,
                      const f16* __restrict__ a1_hi, const f16* __restrict__ a1_lo,
                      const float* __restrict__ w_ih, const float* __restrict__ w_hh,
                      float* __restrict__ gg2) {
  // 4 planes: Ahi|Alo|Bhi|Blo; each [kg 0..3, stride 68][row 0..63] of f16x8 atoms
  __shared__ f16x8 atoms[4 * 272];   // 17408 B
  f16x8* Ahi = atoms;
  f16x8* Alo = atoms + 272;
  f16x8* Bhi = atoms + 544;
  f16x8* Blo = atoms + 816;

  const int tid = threadIdx.x;
  const int lane = tid & 63;
  const int wave = tid >> 6;
  const int wm = wave >> 1, wn = wave & 1;
  const int l15 = lane & 15, l4 = lane >> 4;
  const int n0g = blockIdx.x * 64;   // 0..6080
  const int m0 = blockIdx.y * 64;    // 0..192
  const int kb = blockIdx.z * 512;   // K-half

  const f16 *ahi, *alo; const float* W; int nc;
  if (n0g < 3072) { ahi = a0_hi; alo = a0_lo; W = w_ih; nc = n0g; }
  else            { ahi = a1_hi; alo = a1_lo; W = w_hh; nc = n0g - 3072; }

  f32x4 acc[2][2];
  #pragma unroll
  for (int mi = 0; mi < 2; ++mi)
    #pragma unroll
    for (int ni = 0; ni < 2; ++ni) acc[mi][ni] = (f32x4){0.f, 0.f, 0.f, 0.f};

  // staging role: row sr = tid>>2 (0..63), k-group skg = tid&3
  const int sr = tid >> 2, skg = tid & 3;
  const int satom = skg * 68 + sr;
  const f16* agh = ahi + (size_t)(m0 + sr) * HD + kb + skg * 8;
  const f16* agl = alo + (size_t)(m0 + sr) * HD + kb + skg * 8;
  const float* wgp = W + (size_t)(nc + sr) * HD + kb + skg * 8;

  for (int kt = 0; kt < 16; ++kt) {
    const int k0 = kt * 32;
    // global -> regs (coalesced: 4 lanes cover 32B (A, f16) / 128B (W, fp32) per row)
    f16x8 rah = *(const f16x8*)(agh + k0);
    f16x8 ral = *(const f16x8*)(agl + k0);
    float4 w0 = *(const float4*)(wgp + k0);
    float4 w1 = *(const float4*)(wgp + k0 + 4);
    f16x8 wbh, wbl;
    {
      float wv[8] = {w0.x, w0.y, w0.z, w0.w, w1.x, w1.y, w1.z, w1.w};
      #pragma unroll
      for (int j = 0; j < 8; ++j) {
        f16 h = (f16)wv[j];
        wbh[j] = h;
        wbl[j] = (f16)(wv[j] - (float)h);
      }
    }
    __syncthreads();            // previous tile's fragment reads complete
    Ahi[satom] = rah;
    Alo[satom] = ral;
    Bhi[satom] = wbh;
    Blo[satom] = wbl;
    __syncthreads();            // tile visible

    f16x8 fah[2], fal[2], fbh[2], fbl[2];
    #pragma unroll
    for (int mi = 0; mi < 2; ++mi) {
      int idx = l4 * 68 + wm * 32 + mi * 16 + l15;
      fah[mi] = Ahi[idx]; fal[mi] = Alo[idx];
    }
    #pragma unroll
    for (int ni = 0; ni < 2; ++ni) {
      int idx = l4 * 68 + wn * 32 + ni * 16 + l15;
      fbh[ni] = Bhi[idx]; fbl[ni] = Blo[idx];
    }
    #pragma unroll
    for (int mi = 0; mi < 2; ++mi)
      #pragma unroll
      for (int ni = 0; ni < 2; ++ni) {
        acc[mi][ni] = __builtin_amdgcn_mfma_f32_16x16x32_f16(fah[mi], fbh[ni], acc[mi][ni], 0, 0, 0);
        acc[mi][ni] = __builtin_amdgcn_mfma_f32_16x16x32_f16(fah[mi], fbl[ni], acc[mi][ni], 0, 0, 0);
        acc[mi][ni] = __builtin_amdgcn_mfma_f32_16x16x32_f16(fal[mi], fbh[ni], acc[mi][ni], 0, 0, 0);
      }
  }

  float* outp = gg2 + (size_t)blockIdx.z * NBATCH * 6144;
  #pragma unroll
  for (int mi = 0; mi < 2; ++mi)
    #pragma unroll
    for (int ni = 0; ni < 2; ++ni) {
      const int col = n0g + wn * 32 + ni * 16 + l15;
      #pragma unroll
      for (int r = 0; r < 4; ++r) {
        const int row = m0 + wm * 32 + mi * 16 + l4 * 4 + r;
        outp[(size_t)row * 6144 + col] = acc[mi][ni][r];
      }
    }
}

// ================= GRU gates over K-split partials; h carried as (hi,lo) =================
static __device__ __forceinline__ float4 add4_(float4 a, float4 b) {
  float4 r; r.x = a.x + b.x; r.y = a.y + b.y; r.z = a.z + b.z; r.w = a.w + b.w; return r;
}
__global__ void gru_gates_split2_k(const float* __restrict__ gg2,
                                   const float* __restrict__ b_ih, const float* __restrict__ b_hh,
                                   const f16* __restrict__ hold_hi, const f16* __restrict__ hold_lo,
                                   f16* __restrict__ hnew_hi, f16* __restrict__ hnew_lo) {
  int idx = blockIdx.x * 256 + threadIdx.x;   // 65536
  int b = idx >> 8;
  int k4 = (idx & 255) << 2;
  const float* g0 = gg2 + (size_t)b * 6144;
  const float* g1 = gg2 + (size_t)NBATCH * 6144 + (size_t)b * 6144;
  #define LD2(off) add4_(*(const float4*)(g0 + (off) + k4), *(const float4*)(g1 + (off) + k4))
  float4 gir = LD2(0);
  float4 giz = LD2(1024);
  float4 gin = LD2(2048);
  float4 ghr = LD2(3072);
  float4 ghz = LD2(4096);
  float4 ghn = LD2(5120);
  #undef LD2
  float4 bir = *(const float4*)(b_ih + k4);
  float4 biz = *(const float4*)(b_ih + 1024 + k4);
  float4 bin = *(const float4*)(b_ih + 2048 + k4);
  float4 bhr = *(const float4*)(b_hh + k4);
  float4 bhz = *(const float4*)(b_hh + 1024 + k4);
  float4 bhn = *(const float4*)(b_hh + 2048 + k4);
  f16x4 hh = *(const f16x4*)(hold_hi + (size_t)b * HD + k4);
  f16x4 hl = *(const f16x4*)(hold_lo + (size_t)b * HD + k4);
  float hov[4];
  #pragma unroll
  for (int j = 0; j < 4; ++j) hov[j] = (float)hh[j] + (float)hl[j];
  float4 ho; ho.x = hov[0]; ho.y = hov[1]; ho.z = hov[2]; ho.w = hov[3];
  float4 o;
  #define GATE(c) { \
    float rr = sigmoidf_(gir.c + bir.c + ghr.c + bhr.c); \
    float zz = sigmoidf_(giz.c + biz.c + ghz.c + bhz.c); \
    float nn = tanhf(gin.c + bin.c + rr * (ghn.c + bhn.c)); \
    o.c = (1.0f - zz) * nn + zz * ho.c; }
  GATE(x) GATE(y) GATE(z) GATE(w)
  #undef GATE
  float vv[4] = {o.x, o.y, o.z, o.w};
  f16x4 h4, l4;
  #pragma unroll
  for (int j = 0; j < 4; ++j) {
    f16 h = (f16)vv[j];
    h4[j] = h;
    l4[j] = (f16)(vv[j] - (float)h);
  }
  *(f16x4*)(hnew_hi + (size_t)b * HD + k4) = h4;
  *(f16x4*)(hnew_lo + (size_t)b * HD + k4) = l4;
}

// ================= logits GEMM, f16 MFMA (padded LDS atoms, dst/stride param) ========
// LDS layout: kg-row of 132 atoms (2112 B), 4 kg-rows = 8448 B. STAGE j writes the
// (j>>1)-th kg-row's half (j&1): base = (j>>1)*2112 + (j&1)*1024 bytes, linear per wave.
__global__ __launch_bounds__(256)
void gemm_logits_f16_k(const f16* __restrict__ xf, const f16* __restrict__ wf,
                       const float* __restrict__ bias, float* __restrict__ out,
                       long row_stride) {
  __shared__ f16 lb_raw[4224];                 // 8448 B
  const int tid = threadIdx.x;
  const int lane = tid & 63;
  const int wave = tid >> 6;
  const int wm = wave >> 1, wn = wave & 1;
  const int l15 = lane & 15, l4 = lane >> 4;
  const int n0 = blockIdx.x * 128;
  const int m0 = blockIdx.y * 128;

  f32x4 acc[4][4];
  #pragma unroll
  for (int mi = 0; mi < 4; ++mi)
    #pragma unroll
    for (int ni = 0; ni < 4; ++ni) acc[mi][ni] = (f32x4){0.f, 0.f, 0.f, 0.f};

  f16x8 a_cur[4], a_nxt[4];

  #define STAGE(k0) { \
    _Pragma("unroll") \
    for (int jj = 0; jj < 2; ++jj) { \
      int j = wave * 2 + jj; \
      int a = j * 64 + lane; \
      int n = a & 127, kg = a >> 7; \
      const f16* src = wf + (size_t)(n0 + n) * 1024 + (k0) + kg * 8; \
      __builtin_amdgcn_global_load_lds((const GLOBAL_AS void*)src, \
          (LDS_AS void*)(lb_raw + (size_t)(j >> 1) * 1056 + (size_t)(j & 1) * 512), 16, 0, 0); \
    } }
  #define LOADA(k0, dst) { \
    _Pragma("unroll") \
    for (int mi = 0; mi < 4; ++mi) { \
      int row = m0 + wm * 64 + mi * 16 + l15; \
      dst[mi] = *(const f16x8*)(xf + (size_t)row * 1024 + (k0) + l4 * 8); \
    } }

  STAGE(0);
  LOADA(0, a_cur);
  __syncthreads();

  for (int kt = 0; kt < 32; ++kt) {
    f16x8 b[4];
    #pragma unroll
    for (int ni = 0; ni < 4; ++ni) {
      int nl = wn * 64 + ni * 16 + l15;
      b[ni] = *(const f16x8*)(lb_raw + (size_t)l4 * 1056 + (size_t)nl * 8);
    }
    if (kt < 31) LOADA((kt + 1) * 32, a_nxt);
    __syncthreads();
    if (kt < 31) STAGE((kt + 1) * 32);
    #pragma unroll
    for (int mi = 0; mi < 4; ++mi)
      #pragma unroll
      for (int ni = 0; ni < 4; ++ni)
        acc[mi][ni] = __builtin_amdgcn_mfma_f32_16x16x32_f16(a_cur[mi], b[ni], acc[mi][ni], 0, 0, 0);
    __syncthreads();
    #pragma unroll
    for (int mi = 0; mi < 4; ++mi) a_cur[mi] = a_nxt[mi];
  }
  #undef STAGE
  #undef LOADA

  #pragma unroll
  for (int mi = 0; mi < 4; ++mi)
    #pragma unroll
    for (int ni = 0; ni < 4; ++ni) {
      const int col = n0 + wn * 64 + ni * 16 + l15;
      const float bv = bias[col];
      #pragma unroll
      for (int r = 0; r < 4; ++r) {
        const int row = m0 + wm * 64 + mi * 16 + l4 * 4 + r;
        out[(size_t)row * row_stride + col] = acc[mi][ni][r] + bv;
      }
    }
}

// ================= fused finalize: max -> lse+cands -> write (v-lse) -> rescue ======
__global__ __launch_bounds__(256)
void finalize_k(const float* __restrict__ src, long sstride,
                const f16* __restrict__ xhi, const f16* __restrict__ xlo,
                const float* __restrict__ w, const float* __restrict__ ob,
                float* __restrict__ outp, int* __restrict__ tok) {
  __shared__ float sv[256];
  __shared__ double sd[256];
  __shared__ int scand[64];
  __shared__ int scnt;
  const int b = blockIdx.x;
  const int tid = threadIdx.x;
  const float* row = src + (size_t)b * sstride;

  // pass 1: max
  float vmax = -3.4e38f;
  for (int i = tid; i < VOC; i += 256) vmax = fmaxf(vmax, row[i]);
  sv[tid] = vmax;
  if (tid == 0) scnt = 0;
  __syncthreads();
  for (int off = 128; off; off >>= 1) {
    if (tid < off) sv[tid] = fmaxf(sv[tid], sv[tid + off]);
    __syncthreads();
  }
  const float gmax = sv[0];
  const float thr = gmax - 0.125f;   // f16-GEMM error bound ~0.01 << 0.125
  __syncthreads();

  // pass 2: sum + candidate collection
  float s = 0.0f;
  for (int i = tid; i < VOC; i += 256) {
    float v = row[i];
    s += expf(v - gmax);
    if (v >= thr) {
      int p = atomicAdd(&scnt, 1);
      if (p < 64) scand[p] = i;
    }
  }
  sv[tid] = s;
  __syncthreads();
  for (int off = 128; off; off >>= 1) {
    if (tid < off) sv[tid] += sv[tid + off];
    __syncthreads();
  }
  const float lse = gmax + logf(sv[0]);
  const int c = scnt < 64 ? scnt : 64;
  __syncthreads();

  // pass 3: write log_probs (works in-place when src==outp region)
  float* orow = outp + (size_t)b * OUT_ROW;
  for (int i = tid; i < VOC; i += 256) orow[i] = row[i] - lse;

  // rescue: exact fp64 argmax over candidates (first-index tie-break)
  double best = -1.0e300; int bi = 0;
  for (int j = 0; j < c; ++j) {
    const int idx = scand[j];
    double p = 0.0;
    const f16* xh = xhi + (size_t)b * HD;
    const f16* xl = xlo + (size_t)b * HD;
    const float* wr = w + (size_t)idx * HD;
    for (int k = tid; k < HD; k += 256)
      p += ((double)xh[k] + (double)xl[k]) * (double)wr[k];
    sd[tid] = p;
    __syncthreads();
    for (int off = 128; off; off >>= 1) {
      if (tid < off) sd[tid] += sd[tid + off];
      __syncthreads();
    }
    if (tid == 0) {
      double tot = sd[0] + (double)ob[idx];
      sd[0] = tot;   // broadcast
    }
    __syncthreads();
    double tot = sd[0];
    if (j == 0 || tot > best || (tot == best && idx < bi)) { best = tot; bi = idx; }
    __syncthreads();
  }
  if (tid == 0) tok[b] = bi;
}

// ================= final h output: out = hi + lo =================
__global__ void combine_h_k(const f16* __restrict__ hi, const f16* __restrict__ lo,
                            float* __restrict__ o, int n4) {
  int i = blockIdx.x * 256 + threadIdx.x;
  if (i >= n4) return;
  f16x4 h = ((const f16x4*)hi)[i];
  f16x4 l = ((const f16x4*)lo)[i];
  float4 v;
  v.x = (float)h[0] + (float)l[0];
  v.y = (float)h[1] + (float)l[1];
  v.z = (float)h[2] + (float)l[2];
  v.w = (float)h[3] + (float)l[3];
  ((float4*)o)[i] = v;
}

extern "C" void kernel_launch(void* const* d_in, const int* in_sizes, int n_in,
                              void* d_out, int out_size, void* d_ws, size_t ws_size,
                              hipStream_t stream) {
  (void)in_sizes; (void)n_in; (void)out_size;
  const float* enc_hidden = (const float*)d_in[1];   // [4,256,1024]
  const float* emb   = (const float*)d_in[2];        // [32000,1024]
  const float* w_ih  = (const float*)d_in[3];        // [4,3072,1024]
  const float* w_hh  = (const float*)d_in[4];        // [4,3072,1024]
  const float* b_ih  = (const float*)d_in[5];        // [4,3072]
  const float* b_hh  = (const float*)d_in[6];        // [4,3072]
  const float* out_w = (const float*)d_in[7];        // [32000,1024]
  const float* out_b = (const float*)d_in[8];        // [32000]
  float* out = (float*)d_out;

  size_t off = 0;
  char* base = (char*)d_ws;
  #define WSALLOC(bytes) ((void*)(base + off)); off += (((size_t)(bytes)) + 255) & ~(size_t)255
  float* gg2   = (float*) WSALLOC((size_t)2 * NBATCH * 6144 * 4);  // 12.6 MB
  f16*   hs_hi = (f16*)   WSALLOC(2 * 4 * BH * 2);                 // 4.2 MB
  f16*   hs_lo = (f16*)   WSALLOC(2 * 4 * BH * 2);                 // 4.2 MB
  f16*   xs_hi = (f16*)   WSALLOC(BH * 2);                         // 0.5 MB
  f16*   xs_lo = (f16*)   WSALLOC(BH * 2);                         // 0.5 MB
  int*   tok   = (int*)   WSALLOC(1024);
  float* lse_u = (float*) WSALLOC(1024);  (void)lse_u;
  int*   cand_u= (int*)   WSALLOC((size_t)NBATCH * 64 * 4); (void)cand_u;
  int*   cnt_u = (int*)   WSALLOC(1024);  (void)cnt_u;
  f16*   wf16  = (f16*)   WSALLOC((size_t)VOC * HD * 2);           // 65.5 MB
  const size_t need_base = off;                                    // ~87.6 MB (proven fits)
  float* lgws  = (float*) WSALLOC((size_t)NBATCH * VOC * 4);       // +32.8 MB scratch logits
  #undef WSALLOC
  if (need_base > ws_size) return;                 // can't run at all (will fail loudly)
  const bool scratch = (off <= ws_size);           // logits->ws tier if it fits

  // one-time conversions
  f32_to_f16_k<<<2048, 256, 0, stream>>>(out_w, wf16, (long)VOC * HD / 8);
  split_f32_k<<<512, 256, 0, stream>>>(enc_hidden, hs_hi, hs_lo, (long)(4 * BH / 8));
  hipMemsetAsync(tok, 0, NBATCH * 4, stream);

  int p = 0;
  for (int t = 0; t < TSTEPS; ++t) {
    f16* hp_hi = hs_hi + (size_t)p * 4 * BH;
    f16* hp_lo = hs_lo + (size_t)p * 4 * BH;
    f16* hn_hi = hs_hi + (size_t)(1 - p) * 4 * BH;
    f16* hn_lo = hs_lo + (size_t)(1 - p) * 4 * BH;

    embed_relu_split_k<<<256, 256, 0, stream>>>(emb, tok, xs_hi, xs_lo);

    for (int l = 0; l < 4; ++l) {
      const f16* a0hi = (l == 0) ? xs_hi : hn_hi + (size_t)(l - 1) * BH;
      const f16* a0lo = (l == 0) ? xs_lo : hn_lo + (size_t)(l - 1) * BH;
      gemm_gru_mfma3_k<<<dim3(96, 4, 2), 256, 0, stream>>>(
          a0hi, a0lo, hp_hi + (size_t)l * BH, hp_lo + (size_t)l * BH,
          w_ih + (size_t)l * 3072 * HD, w_hh + (size_t)l * 3072 * HD, gg2);
      gru_gates_split2_k<<<256, 256, 0, stream>>>(
          gg2, b_ih + l * 3072, b_hh + l * 3072,
          hp_hi + (size_t)l * BH, hp_lo + (size_t)l * BH,
          hn_hi + (size_t)l * BH, hn_lo + (size_t)l * BH);
    }

    float* lg_out = out + (size_t)t * VOC;
    float* dst    = scratch ? lgws : lg_out;
    long   dstr   = scratch ? (long)VOC : OUT_ROW;
    gemm_logits_f16_k<<<dim3(250, 2), 256, 0, stream>>>(
        hn_hi + (size_t)3 * BH, wf16, out_b, dst, dstr);
    finalize_k<<<NBATCH, 256, 0, stream>>>(
        dst, dstr, hn_hi + (size_t)3 * BH, hn_lo + (size_t)3 * BH,
        out_w, out_b, lg_out, tok);

    p ^= 1;
  }

  // after 20 steps the final h splits sit in parity 0; 4*BH floats = 262,144 float4
  combine_h_k<<<1024, 256, 0, stream>>>(hs_hi, hs_lo,
                                        out + (size_t)NBATCH * TSTEPS * VOC,
                                        (int)(4 * BH / 4));
}

// Round 7
// 6138.614 us; speedup vs baseline: 2.0652x; 1.0162x over previous
//
#include <hip/hip_runtime.h>
#include <math.h>

#define HD 1024
#define NBATCH 256
#define VOC 32000
#define TSTEPS 20
#define OUT_ROW 640000LL   // 20*32000, row stride (floats) between b rows in d_out
#define BH ((size_t)NBATCH * HD)

typedef _Float16 f16;
typedef __attribute__((ext_vector_type(4))) _Float16 f16x4;
typedef __attribute__((ext_vector_type(8))) _Float16 f16x8;
typedef __attribute__((ext_vector_type(4))) float f32x4;

#define GLOBAL_AS __attribute__((address_space(1)))
#define LDS_AS    __attribute__((address_space(3)))

static __device__ __forceinline__ float sigmoidf_(float v) {
  return 1.0f / (1.0f + expf(-v));
}

// ================= conversion kernels =================

__global__ void f32_to_f16_k(const float* __restrict__ in, f16* __restrict__ out, long n8) {
  long i = (long)blockIdx.x * 256 + threadIdx.x;
  long stride = (long)gridDim.x * 256;
  for (; i < n8; i += stride) {
    float4 a = *((const float4*)in + i * 2);
    float4 b = *((const float4*)in + i * 2 + 1);
    f16x8 o;
    o[0] = (f16)a.x; o[1] = (f16)a.y; o[2] = (f16)a.z; o[3] = (f16)a.w;
    o[4] = (f16)b.x; o[5] = (f16)b.y; o[6] = (f16)b.z; o[7] = (f16)b.w;
    *((f16x8*)out + i) = o;
  }
}

__global__ void split_f32_k(const float* __restrict__ in, f16* __restrict__ hi,
                            f16* __restrict__ lo, long n8) {
  long i = (long)blockIdx.x * 256 + threadIdx.x;
  long stride = (long)gridDim.x * 256;
  for (; i < n8; i += stride) {
    float4 a = *((const float4*)in + i * 2);
    float4 b = *((const float4*)in + i * 2 + 1);
    float v[8] = {a.x, a.y, a.z, a.w, b.x, b.y, b.z, b.w};
    f16x8 h8, l8;
    #pragma unroll
    for (int j = 0; j < 8; ++j) {
      f16 h = (f16)v[j];
      h8[j] = h;
      l8[j] = (f16)(v[j] - (float)h);
    }
    *((f16x8*)hi + i) = h8;
    *((f16x8*)lo + i) = l8;
  }
}

// ================= GRU GEMM v4: double-buffered LDS, embed-fused layer 0 =========
// gg2[z][b][0:3072] = x @ w_ih^T (K-half z) ; gg2[z][b][3072:6144] = h @ w_hh^T
// tile 64(M) x 64(N), 4 waves (2x2 of 32x32), K-split x2 (z), BK=32, 1 barrier/iter.
// use_emb: layer-0 mode, A(x) = relu(emb[tok[row]]) split in-register.
__global__ __launch_bounds__(256)
void gemm_gru_mfma4_k(const f16* __restrict__ a0_hi, const f16* __restrict__ a0_lo,
                      const f16* __restrict__ a1_hi, const f16* __restrict__ a1_lo,
                      const float* __restrict__ emb, const int* __restrict__ tok, int use_emb,
                      const float* __restrict__ w_ih, const float* __restrict__ w_hh,
                      float* __restrict__ gg2) {
  // per buffer: 4 planes (Ahi|Alo|Bhi|Blo), each [kg 0..3 stride 68][row 0..63]
  __shared__ f16x8 atoms[2][1088];   // 2 x 17408 B

  const int tid = threadIdx.x;
  const int lane = tid & 63;
  const int wave = tid >> 6;
  const int wm = wave >> 1, wn = wave & 1;
  const int l15 = lane & 15, l4 = lane >> 4;
  const int n0g = blockIdx.x * 64;   // 0..6080
  const int m0 = blockIdx.y * 64;    // 0..192
  const int kb = blockIdx.z * 512;   // K-half

  const f16 *ahi, *alo; const float* W; int nc;
  if (n0g < 3072) { ahi = a0_hi; alo = a0_lo; W = w_ih; nc = n0g; }
  else            { ahi = a1_hi; alo = a1_lo; W = w_hh; nc = n0g - 3072; }
  const bool embmode = use_emb && (n0g < 3072);

  f32x4 acc[2][2];
  #pragma unroll
  for (int mi = 0; mi < 2; ++mi)
    #pragma unroll
    for (int ni = 0; ni < 2; ++ni) acc[mi][ni] = (f32x4){0.f, 0.f, 0.f, 0.f};

  // staging role: row sr = tid>>2 (0..63), k-group skg = tid&3
  const int sr = tid >> 2, skg = tid & 3;
  const int satom = skg * 68 + sr;
  const float* wgp = W + (size_t)(nc + sr) * HD + kb + skg * 8;
  const f16* agh = ahi + (size_t)(m0 + sr) * HD + kb + skg * 8;
  const f16* agl = alo + (size_t)(m0 + sr) * HD + kb + skg * 8;
  const float* egp = embmode ? (emb + (size_t)tok[m0 + sr] * HD + kb + skg * 8) : wgp;

  // load + split into regs for k-offset k0
  #define LOADREGS(k0, rah, ral, wbh, wbl) { \
    if (embmode) { \
      float4 e0 = *(const float4*)(egp + (k0)); \
      float4 e1 = *(const float4*)(egp + (k0) + 4); \
      float av[8] = {fmaxf(e0.x,0.f), fmaxf(e0.y,0.f), fmaxf(e0.z,0.f), fmaxf(e0.w,0.f), \
                     fmaxf(e1.x,0.f), fmaxf(e1.y,0.f), fmaxf(e1.z,0.f), fmaxf(e1.w,0.f)}; \
      _Pragma("unroll") \
      for (int j = 0; j < 8; ++j) { \
        f16 h = (f16)av[j]; rah[j] = h; ral[j] = (f16)(av[j] - (float)h); \
      } \
    } else { \
      rah = *(const f16x8*)(agh + (k0)); \
      ral = *(const f16x8*)(agl + (k0)); \
    } \
    float4 w0 = *(const float4*)(wgp + (k0)); \
    float4 w1 = *(const float4*)(wgp + (k0) + 4); \
    float wv[8] = {w0.x, w0.y, w0.z, w0.w, w1.x, w1.y, w1.z, w1.w}; \
    _Pragma("unroll") \
    for (int j = 0; j < 8; ++j) { \
      f16 h = (f16)wv[j]; wbh[j] = h; wbl[j] = (f16)(wv[j] - (float)h); \
    } }

  {
    f16x8 rah, ral, wbh, wbl;
    LOADREGS(0, rah, ral, wbh, wbl);
    atoms[0][satom]       = rah;
    atoms[0][272 + satom] = ral;
    atoms[0][544 + satom] = wbh;
    atoms[0][816 + satom] = wbl;
  }
  __syncthreads();

  for (int kt = 0; kt < 16; ++kt) {
    const int cur = kt & 1;
    f16x8 nah, nal, nbh, nbl;
    if (kt < 15) { LOADREGS((kt + 1) * 32, nah, nal, nbh, nbl); }

    f16x8 fah[2], fal[2], fbh[2], fbl[2];
    #pragma unroll
    for (int mi = 0; mi < 2; ++mi) {
      int idx = l4 * 68 + wm * 32 + mi * 16 + l15;
      fah[mi] = atoms[cur][idx];
      fal[mi] = atoms[cur][272 + idx];
    }
    #pragma unroll
    for (int ni = 0; ni < 2; ++ni) {
      int idx = l4 * 68 + wn * 32 + ni * 16 + l15;
      fbh[ni] = atoms[cur][544 + idx];
      fbl[ni] = atoms[cur][816 + idx];
    }
    #pragma unroll
    for (int mi = 0; mi < 2; ++mi)
      #pragma unroll
      for (int ni = 0; ni < 2; ++ni) {
        acc[mi][ni] = __builtin_amdgcn_mfma_f32_16x16x32_f16(fah[mi], fbh[ni], acc[mi][ni], 0, 0, 0);
        acc[mi][ni] = __builtin_amdgcn_mfma_f32_16x16x32_f16(fah[mi], fbl[ni], acc[mi][ni], 0, 0, 0);
        acc[mi][ni] = __builtin_amdgcn_mfma_f32_16x16x32_f16(fal[mi], fbh[ni], acc[mi][ni], 0, 0, 0);
      }

    if (kt < 15) {
      atoms[cur ^ 1][satom]       = nah;
      atoms[cur ^ 1][272 + satom] = nal;
      atoms[cur ^ 1][544 + satom] = nbh;
      atoms[cur ^ 1][816 + satom] = nbl;
    }
    __syncthreads();
  }
  #undef LOADREGS

  float* outp = gg2 + (size_t)blockIdx.z * NBATCH * 6144;
  #pragma unroll
  for (int mi = 0; mi < 2; ++mi)
    #pragma unroll
    for (int ni = 0; ni < 2; ++ni) {
      const int col = n0g + wn * 32 + ni * 16 + l15;
      #pragma unroll
      for (int r = 0; r < 4; ++r) {
        const int row = m0 + wm * 32 + mi * 16 + l4 * 4 + r;
        outp[(size_t)row * 6144 + col] = acc[mi][ni][r];
      }
    }
}

// ================= GRU gates over K-split partials; h carried as (hi,lo) =================
static __device__ __forceinline__ float4 add4_(float4 a, float4 b) {
  float4 r; r.x = a.x + b.x; r.y = a.y + b.y; r.z = a.z + b.z; r.w = a.w + b.w; return r;
}
__global__ void gru_gates_split2_k(const float* __restrict__ gg2,
                                   const float* __restrict__ b_ih, const float* __restrict__ b_hh,
                                   const f16* __restrict__ hold_hi, const f16* __restrict__ hold_lo,
                                   f16* __restrict__ hnew_hi, f16* __restrict__ hnew_lo) {
  int idx = blockIdx.x * 256 + threadIdx.x;   // 65536
  int b = idx >> 8;
  int k4 = (idx & 255) << 2;
  const float* g0 = gg2 + (size_t)b * 6144;
  const float* g1 = gg2 + (size_t)NBATCH * 6144 + (size_t)b * 6144;
  #define LD2(off) add4_(*(const float4*)(g0 + (off) + k4), *(const float4*)(g1 + (off) + k4))
  float4 gir = LD2(0);
  float4 giz = LD2(1024);
  float4 gin = LD2(2048);
  float4 ghr = LD2(3072);
  float4 ghz = LD2(4096);
  float4 ghn = LD2(5120);
  #undef LD2
  float4 bir = *(const float4*)(b_ih + k4);
  float4 biz = *(const float4*)(b_ih + 1024 + k4);
  float4 bin = *(const float4*)(b_ih + 2048 + k4);
  float4 bhr = *(const float4*)(b_hh + k4);
  float4 bhz = *(const float4*)(b_hh + 1024 + k4);
  float4 bhn = *(const float4*)(b_hh + 2048 + k4);
  f16x4 hh = *(const f16x4*)(hold_hi + (size_t)b * HD + k4);
  f16x4 hl = *(const f16x4*)(hold_lo + (size_t)b * HD + k4);
  float hov[4];
  #pragma unroll
  for (int j = 0; j < 4; ++j) hov[j] = (float)hh[j] + (float)hl[j];
  float4 ho; ho.x = hov[0]; ho.y = hov[1]; ho.z = hov[2]; ho.w = hov[3];
  float4 o;
  #define GATE(c) { \
    float rr = sigmoidf_(gir.c + bir.c + ghr.c + bhr.c); \
    float zz = sigmoidf_(giz.c + biz.c + ghz.c + bhz.c); \
    float nn = tanhf(gin.c + bin.c + rr * (ghn.c + bhn.c)); \
    o.c = (1.0f - zz) * nn + zz * ho.c; }
  GATE(x) GATE(y) GATE(z) GATE(w)
  #undef GATE
  float vv[4] = {o.x, o.y, o.z, o.w};
  f16x4 h4, l4;
  #pragma unroll
  for (int j = 0; j < 4; ++j) {
    f16 h = (f16)vv[j];
    h4[j] = h;
    l4[j] = (f16)(vv[j] - (float)h);
  }
  *(f16x4*)(hnew_hi + (size_t)b * HD + k4) = h4;
  *(f16x4*)(hnew_lo + (size_t)b * HD + k4) = l4;
}

// ================= logits GEMM v2: BM=256 x BN=64, double-buffered B =================
// 4 waves each own a 64x64 tile (wave = m-slice); B panel read ONCE per dispatch.
// LDS per buffer: 4 kg-rows x 66 atoms (1056 B padded) = 4224 B; 1 barrier/iter.
__global__ __launch_bounds__(256)
void gemm_logits2_k(const f16* __restrict__ xf, const f16* __restrict__ wf,
                    const float* __restrict__ bias, float* __restrict__ out,
                    long row_stride) {
  __shared__ f16 lb[2][2112];                 // 2 x 4224 B
  const int tid = threadIdx.x;
  const int lane = tid & 63;
  const int wave = tid >> 6;
  const int l15 = lane & 15, l4 = lane >> 4;
  const int n0 = blockIdx.x * 64;

  f32x4 acc[4][4];
  #pragma unroll
  for (int mi = 0; mi < 4; ++mi)
    #pragma unroll
    for (int ni = 0; ni < 4; ++ni) acc[mi][ni] = (f32x4){0.f, 0.f, 0.f, 0.f};

  f16x8 a_cur[4], a_nxt[4];

  // wave stages kg-row = wave: 64 lanes x 16B, linear into padded row (1056 B)
  #define STAGE(k0, buf) { \
    const f16* src = wf + (size_t)(n0 + lane) * 1024 + (k0) + wave * 8; \
    __builtin_amdgcn_global_load_lds((const GLOBAL_AS void*)src, \
        (LDS_AS void*)(lb[buf] + wave * 528), 16, 0, 0); }
  #define LOADA(k0, dst) { \
    _Pragma("unroll") \
    for (int mi = 0; mi < 4; ++mi) { \
      int row = wave * 64 + mi * 16 + l15; \
      dst[mi] = *(const f16x8*)(xf + (size_t)row * 1024 + (k0) + l4 * 8); \
    } }

  STAGE(0, 0);
  LOADA(0, a_cur);
  __syncthreads();

  for (int kt = 0; kt < 32; ++kt) {
    const int cur = kt & 1;
    f16x8 b[4];
    #pragma unroll
    for (int ni = 0; ni < 4; ++ni)
      b[ni] = *(const f16x8*)(lb[cur] + (size_t)l4 * 528 + (size_t)(ni * 16 + l15) * 8);
    if (kt < 31) {
      STAGE((kt + 1) * 32, cur ^ 1);
      LOADA((kt + 1) * 32, a_nxt);
    }
    #pragma unroll
    for (int mi = 0; mi < 4; ++mi)
      #pragma unroll
      for (int ni = 0; ni < 4; ++ni)
        acc[mi][ni] = __builtin_amdgcn_mfma_f32_16x16x32_f16(a_cur[mi], b[ni], acc[mi][ni], 0, 0, 0);
    __syncthreads();
    #pragma unroll
    for (int mi = 0; mi < 4; ++mi) a_cur[mi] = a_nxt[mi];
  }
  #undef STAGE
  #undef LOADA

  #pragma unroll
  for (int mi = 0; mi < 4; ++mi)
    #pragma unroll
    for (int ni = 0; ni < 4; ++ni) {
      const int col = n0 + ni * 16 + l15;
      const float bv = bias[col];
      #pragma unroll
      for (int r = 0; r < 4; ++r) {
        const int row = wave * 64 + mi * 16 + l4 * 4 + r;
        out[(size_t)row * row_stride + col] = acc[mi][ni][r] + bv;
      }
    }
}

// ================= fused finalize v2: online max+sum -> write+cands -> rescue ======
__global__ __launch_bounds__(256)
void finalize2_k(const float* __restrict__ src, long sstride,
                 const f16* __restrict__ xhi, const f16* __restrict__ xlo,
                 const float* __restrict__ w, const float* __restrict__ ob,
                 float* __restrict__ outp, int* __restrict__ tok) {
  __shared__ float sm[256];
  __shared__ float ssum[256];
  __shared__ double sd[256];
  __shared__ int scand[64];
  __shared__ int scnt;
  const int b = blockIdx.x;
  const int tid = threadIdx.x;
  const float4* row = (const float4*)(src + (size_t)b * sstride);   // 8000 float4

  // pass A: online max + sum
  float m = -3.4e38f, s = 0.0f;
  for (int i = tid; i < 8000; i += 256) {
    float4 v = row[i];
    float mx = fmaxf(fmaxf(v.x, v.y), fmaxf(v.z, v.w));
    if (mx > m) { s *= expf(m - mx); m = mx; }
    s += expf(v.x - m) + expf(v.y - m) + expf(v.z - m) + expf(v.w - m);
  }
  sm[tid] = m; ssum[tid] = s;
  if (tid == 0) scnt = 0;
  __syncthreads();
  for (int off = 128; off; off >>= 1) {
    if (tid < off) {
      float m1 = sm[tid], m2 = sm[tid + off];
      float M = fmaxf(m1, m2);
      ssum[tid] = ssum[tid] * expf(m1 - M) + ssum[tid + off] * expf(m2 - M);
      sm[tid] = M;
    }
    __syncthreads();
  }
  const float gmax = sm[0];
  const float lse = gmax + logf(ssum[0]);
  const float thr = gmax - 0.25f;   // 2x the ~0.09 f16-GEMM error bound, with margin
  __syncthreads();

  // pass B: write log_probs + collect candidates (in-place safe: read-then-write)
  float4* orow = (float4*)(outp + (size_t)b * OUT_ROW);
  for (int i = tid; i < 8000; i += 256) {
    float4 v = row[i];
    if (v.x >= thr || v.y >= thr || v.z >= thr || v.w >= thr) {
      float e[4] = {v.x, v.y, v.z, v.w};
      #pragma unroll
      for (int j = 0; j < 4; ++j)
        if (e[j] >= thr) {
          int p = atomicAdd(&scnt, 1);
          if (p < 64) scand[p] = i * 4 + j;
        }
    }
    float4 o; o.x = v.x - lse; o.y = v.y - lse; o.z = v.z - lse; o.w = v.w - lse;
    orow[i] = o;
  }
  __syncthreads();
  const int c = scnt < 64 ? scnt : 64;

  // rescue: exact fp64 argmax over candidates (first-index tie-break, order-free)
  double best = -1.0e300; int bi = 0;
  for (int j = 0; j < c; ++j) {
    const int idx = scand[j];
    double p = 0.0;
    const f16* xh = xhi + (size_t)b * HD;
    const f16* xl = xlo + (size_t)b * HD;
    const float* wr = w + (size_t)idx * HD;
    for (int k = tid; k < HD; k += 256)
      p += ((double)xh[k] + (double)xl[k]) * (double)wr[k];
    sd[tid] = p;
    __syncthreads();
    for (int off = 128; off; off >>= 1) {
      if (tid < off) sd[tid] += sd[tid + off];
      __syncthreads();
    }
    if (tid == 0) sd[0] += (double)ob[idx];
    __syncthreads();
    double tot = sd[0];
    if (j == 0 || tot > best || (tot == best && idx < bi)) { best = tot; bi = idx; }
    __syncthreads();
  }
  if (tid == 0) tok[b] = bi;
}

// ================= final h output: out = hi + lo =================
__global__ void combine_h_k(const f16* __restrict__ hi, const f16* __restrict__ lo,
                            float* __restrict__ o, int n4) {
  int i = blockIdx.x * 256 + threadIdx.x;
  if (i >= n4) return;
  f16x4 h = ((const f16x4*)hi)[i];
  f16x4 l = ((const f16x4*)lo)[i];
  float4 v;
  v.x = (float)h[0] + (float)l[0];
  v.y = (float)h[1] + (float)l[1];
  v.z = (float)h[2] + (float)l[2];
  v.w = (float)h[3] + (float)l[3];
  ((float4*)o)[i] = v;
}

extern "C" void kernel_launch(void* const* d_in, const int* in_sizes, int n_in,
                              void* d_out, int out_size, void* d_ws, size_t ws_size,
                              hipStream_t stream) {
  (void)in_sizes; (void)n_in; (void)out_size;
  const float* enc_hidden = (const float*)d_in[1];   // [4,256,1024]
  const float* emb   = (const float*)d_in[2];        // [32000,1024]
  const float* w_ih  = (const float*)d_in[3];        // [4,3072,1024]
  const float* w_hh  = (const float*)d_in[4];        // [4,3072,1024]
  const float* b_ih  = (const float*)d_in[5];        // [4,3072]
  const float* b_hh  = (const float*)d_in[6];        // [4,3072]
  const float* out_w = (const float*)d_in[7];        // [32000,1024]
  const float* out_b = (const float*)d_in[8];        // [32000]
  float* out = (float*)d_out;

  size_t off = 0;
  char* base = (char*)d_ws;
  #define WSALLOC(bytes) ((void*)(base + off)); off += (((size_t)(bytes)) + 255) & ~(size_t)255
  float* gg2   = (float*) WSALLOC((size_t)2 * NBATCH * 6144 * 4);  // 12.6 MB
  f16*   hs_hi = (f16*)   WSALLOC(2 * 4 * BH * 2);                 // 4.2 MB
  f16*   hs_lo = (f16*)   WSALLOC(2 * 4 * BH * 2);                 // 4.2 MB
  int*   tok   = (int*)   WSALLOC(1024);
  f16*   wf16  = (f16*)   WSALLOC((size_t)VOC * HD * 2);           // 65.5 MB
  const size_t need_base = off;                                    // ~86.6 MB
  float* lgws  = (float*) WSALLOC((size_t)NBATCH * VOC * 4);       // +32.8 MB
  #undef WSALLOC
  if (need_base > ws_size) return;                 // fail loudly rather than corrupt
  const bool scratch = (off <= ws_size);           // logits->ws tier if it fits

  // one-time conversions
  f32_to_f16_k<<<2048, 256, 0, stream>>>(out_w, wf16, (long)VOC * HD / 8);
  split_f32_k<<<512, 256, 0, stream>>>(enc_hidden, hs_hi, hs_lo, (long)(4 * BH / 8));
  hipMemsetAsync(tok, 0, NBATCH * 4, stream);

  int p = 0;
  for (int t = 0; t < TSTEPS; ++t) {
    f16* hp_hi = hs_hi + (size_t)p * 4 * BH;
    f16* hp_lo = hs_lo + (size_t)p * 4 * BH;
    f16* hn_hi = hs_hi + (size_t)(1 - p) * 4 * BH;
    f16* hn_lo = hs_lo + (size_t)(1 - p) * 4 * BH;

    for (int l = 0; l < 4; ++l) {
      // layer 0 reads A(x) straight from emb[tok] (embed fused); layers 1-3 from h splits
      const f16* a0hi = (l == 0) ? hs_hi : hn_hi + (size_t)(l - 1) * BH;
      const f16* a0lo = (l == 0) ? hs_lo : hn_lo + (size_t)(l - 1) * BH;
      gemm_gru_mfma4_k<<<dim3(96, 4, 2), 256, 0, stream>>>(
          a0hi, a0lo, hp_hi + (size_t)l * BH, hp_lo + (size_t)l * BH,
          emb, tok, (l == 0) ? 1 : 0,
          w_ih + (size_t)l * 3072 * HD, w_hh + (size_t)l * 3072 * HD, gg2);
      gru_gates_split2_k<<<256, 256, 0, stream>>>(
          gg2, b_ih + l * 3072, b_hh + l * 3072,
          hp_hi + (size_t)l * BH, hp_lo + (size_t)l * BH,
          hn_hi + (size_t)l * BH, hn_lo + (size_t)l * BH);
    }

    float* lg_out = out + (size_t)t * VOC;
    float* dst    = scratch ? lgws : lg_out;
    long   dstr   = scratch ? (long)VOC : OUT_ROW;
    gemm_logits2_k<<<500, 256, 0, stream>>>(
        hn_hi + (size_t)3 * BH, wf16, out_b, dst, dstr);
    finalize2_k<<<NBATCH, 256, 0, stream>>>(
        dst, dstr, hn_hi + (size_t)3 * BH, hn_lo + (size_t)3 * BH,
        out_w, out_b, lg_out, tok);

    p ^= 1;
  }

  // after 20 steps the final h splits sit in parity 0; 4*BH floats = 262,144 float4
  combine_h_k<<<1024, 256, 0, stream>>>(hs_hi, hs_lo,
                                        out + (size_t)NBATCH * TSTEPS * VOC,
                                        (int)(4 * BH / 4));
}

// Round 8
// 4004.479 us; speedup vs baseline: 3.1658x; 1.5329x over previous
//
#include <hip/hip_runtime.h>
#include <math.h>

#define HD 1024
#define NBATCH 256
#define VOC 32000
#define TSTEPS 20
#define OUT_ROW 640000LL   // 20*32000, row stride (floats) between b rows in d_out
#define BH ((size_t)NBATCH * HD)
#define NCHUNK 500         // 32000 / 64
#define THR 0.125f         // candidate window (~100x the f16-GEMM logit error bound)

typedef _Float16 f16;
typedef __attribute__((ext_vector_type(4))) _Float16 f16x4;
typedef __attribute__((ext_vector_type(8))) _Float16 f16x8;
typedef __attribute__((ext_vector_type(4))) float f32x4;

#define GLOBAL_AS __attribute__((address_space(1)))
#define LDS_AS    __attribute__((address_space(3)))

static __device__ __forceinline__ float sigmoidf_(float v) {
  return 1.0f / (1.0f + expf(-v));
}

// ================= conversion kernels =================

__global__ void f32_to_f16_k(const float* __restrict__ in, f16* __restrict__ out, long n8) {
  long i = (long)blockIdx.x * 256 + threadIdx.x;
  long stride = (long)gridDim.x * 256;
  for (; i < n8; i += stride) {
    float4 a = *((const float4*)in + i * 2);
    float4 b = *((const float4*)in + i * 2 + 1);
    f16x8 o;
    o[0] = (f16)a.x; o[1] = (f16)a.y; o[2] = (f16)a.z; o[3] = (f16)a.w;
    o[4] = (f16)b.x; o[5] = (f16)b.y; o[6] = (f16)b.z; o[7] = (f16)b.w;
    *((f16x8*)out + i) = o;
  }
}

__global__ void split_f32_k(const float* __restrict__ in, f16* __restrict__ hi,
                            f16* __restrict__ lo, long n8) {
  long i = (long)blockIdx.x * 256 + threadIdx.x;
  long stride = (long)gridDim.x * 256;
  for (; i < n8; i += stride) {
    float4 a = *((const float4*)in + i * 2);
    float4 b = *((const float4*)in + i * 2 + 1);
    float v[8] = {a.x, a.y, a.z, a.w, b.x, b.y, b.z, b.w};
    f16x8 h8, l8;
    #pragma unroll
    for (int j = 0; j < 8; ++j) {
      f16 h = (f16)v[j];
      h8[j] = h;
      l8[j] = (f16)(v[j] - (float)h);
    }
    *((f16x8*)hi + i) = h8;
    *((f16x8*)lo + i) = l8;
  }
}

// ================= GRU GEMM v4 (validated r7): dbuf LDS, embed-fused layer 0 ======
__global__ __launch_bounds__(256)
void gemm_gru_mfma4_k(const f16* __restrict__ a0_hi, const f16* __restrict__ a0_lo,
                      const f16* __restrict__ a1_hi, const f16* __restrict__ a1_lo,
                      const float* __restrict__ emb, const int* __restrict__ tok, int use_emb,
                      const float* __restrict__ w_ih, const float* __restrict__ w_hh,
                      float* __restrict__ gg2) {
  __shared__ f16x8 atoms[2][1088];   // 2 x 17408 B

  const int tid = threadIdx.x;
  const int lane = tid & 63;
  const int wave = tid >> 6;
  const int wm = wave >> 1, wn = wave & 1;
  const int l15 = lane & 15, l4 = lane >> 4;
  const int n0g = blockIdx.x * 64;   // 0..6080
  const int m0 = blockIdx.y * 64;    // 0..192
  const int kb = blockIdx.z * 512;   // K-half

  const f16 *ahi, *alo; const float* W; int nc;
  if (n0g < 3072) { ahi = a0_hi; alo = a0_lo; W = w_ih; nc = n0g; }
  else            { ahi = a1_hi; alo = a1_lo; W = w_hh; nc = n0g - 3072; }
  const bool embmode = use_emb && (n0g < 3072);

  f32x4 acc[2][2];
  #pragma unroll
  for (int mi = 0; mi < 2; ++mi)
    #pragma unroll
    for (int ni = 0; ni < 2; ++ni) acc[mi][ni] = (f32x4){0.f, 0.f, 0.f, 0.f};

  const int sr = tid >> 2, skg = tid & 3;
  const int satom = skg * 68 + sr;
  const float* wgp = W + (size_t)(nc + sr) * HD + kb + skg * 8;
  const f16* agh = ahi + (size_t)(m0 + sr) * HD + kb + skg * 8;
  const f16* agl = alo + (size_t)(m0 + sr) * HD + kb + skg * 8;
  const float* egp = embmode ? (emb + (size_t)tok[m0 + sr] * HD + kb + skg * 8) : wgp;

  #define LOADREGS(k0, rah, ral, wbh, wbl) { \
    if (embmode) { \
      float4 e0 = *(const float4*)(egp + (k0)); \
      float4 e1 = *(const float4*)(egp + (k0) + 4); \
      float av[8] = {fmaxf(e0.x,0.f), fmaxf(e0.y,0.f), fmaxf(e0.z,0.f), fmaxf(e0.w,0.f), \
                     fmaxf(e1.x,0.f), fmaxf(e1.y,0.f), fmaxf(e1.z,0.f), fmaxf(e1.w,0.f)}; \
      _Pragma("unroll") \
      for (int j = 0; j < 8; ++j) { \
        f16 h = (f16)av[j]; rah[j] = h; ral[j] = (f16)(av[j] - (float)h); \
      } \
    } else { \
      rah = *(const f16x8*)(agh + (k0)); \
      ral = *(const f16x8*)(agl + (k0)); \
    } \
    float4 w0 = *(const float4*)(wgp + (k0)); \
    float4 w1 = *(const float4*)(wgp + (k0) + 4); \
    float wv[8] = {w0.x, w0.y, w0.z, w0.w, w1.x, w1.y, w1.z, w1.w}; \
    _Pragma("unroll") \
    for (int j = 0; j < 8; ++j) { \
      f16 h = (f16)wv[j]; wbh[j] = h; wbl[j] = (f16)(wv[j] - (float)h); \
    } }

  {
    f16x8 rah, ral, wbh, wbl;
    LOADREGS(0, rah, ral, wbh, wbl);
    atoms[0][satom]       = rah;
    atoms[0][272 + satom] = ral;
    atoms[0][544 + satom] = wbh;
    atoms[0][816 + satom] = wbl;
  }
  __syncthreads();

  for (int kt = 0; kt < 16; ++kt) {
    const int cur = kt & 1;
    f16x8 nah, nal, nbh, nbl;
    if (kt < 15) { LOADREGS((kt + 1) * 32, nah, nal, nbh, nbl); }

    f16x8 fah[2], fal[2], fbh[2], fbl[2];
    #pragma unroll
    for (int mi = 0; mi < 2; ++mi) {
      int idx = l4 * 68 + wm * 32 + mi * 16 + l15;
      fah[mi] = atoms[cur][idx];
      fal[mi] = atoms[cur][272 + idx];
    }
    #pragma unroll
    for (int ni = 0; ni < 2; ++ni) {
      int idx = l4 * 68 + wn * 32 + ni * 16 + l15;
      fbh[ni] = atoms[cur][544 + idx];
      fbl[ni] = atoms[cur][816 + idx];
    }
    #pragma unroll
    for (int mi = 0; mi < 2; ++mi)
      #pragma unroll
      for (int ni = 0; ni < 2; ++ni) {
        acc[mi][ni] = __builtin_amdgcn_mfma_f32_16x16x32_f16(fah[mi], fbh[ni], acc[mi][ni], 0, 0, 0);
        acc[mi][ni] = __builtin_amdgcn_mfma_f32_16x16x32_f16(fah[mi], fbl[ni], acc[mi][ni], 0, 0, 0);
        acc[mi][ni] = __builtin_amdgcn_mfma_f32_16x16x32_f16(fal[mi], fbh[ni], acc[mi][ni], 0, 0, 0);
      }

    if (kt < 15) {
      atoms[cur ^ 1][satom]       = nah;
      atoms[cur ^ 1][272 + satom] = nal;
      atoms[cur ^ 1][544 + satom] = nbh;
      atoms[cur ^ 1][816 + satom] = nbl;
    }
    __syncthreads();
  }
  #undef LOADREGS

  float* outp = gg2 + (size_t)blockIdx.z * NBATCH * 6144;
  #pragma unroll
  for (int mi = 0; mi < 2; ++mi)
    #pragma unroll
    for (int ni = 0; ni < 2; ++ni) {
      const int col = n0g + wn * 32 + ni * 16 + l15;
      #pragma unroll
      for (int r = 0; r < 4; ++r) {
        const int row = m0 + wm * 32 + mi * 16 + l4 * 4 + r;
        outp[(size_t)row * 6144 + col] = acc[mi][ni][r];
      }
    }
}

// ================= GRU gates (validated r7) =================
static __device__ __forceinline__ float4 add4_(float4 a, float4 b) {
  float4 r; r.x = a.x + b.x; r.y = a.y + b.y; r.z = a.z + b.z; r.w = a.w + b.w; return r;
}
__global__ void gru_gates_split2_k(const float* __restrict__ gg2,
                                   const float* __restrict__ b_ih, const float* __restrict__ b_hh,
                                   const f16* __restrict__ hold_hi, const f16* __restrict__ hold_lo,
                                   f16* __restrict__ hnew_hi, f16* __restrict__ hnew_lo) {
  int idx = blockIdx.x * 256 + threadIdx.x;   // 65536
  int b = idx >> 8;
  int k4 = (idx & 255) << 2;
  const float* g0 = gg2 + (size_t)b * 6144;
  const float* g1 = gg2 + (size_t)NBATCH * 6144 + (size_t)b * 6144;
  #define LD2(off) add4_(*(const float4*)(g0 + (off) + k4), *(const float4*)(g1 + (off) + k4))
  float4 gir = LD2(0);
  float4 giz = LD2(1024);
  float4 gin = LD2(2048);
  float4 ghr = LD2(3072);
  float4 ghz = LD2(4096);
  float4 ghn = LD2(5120);
  #undef LD2
  float4 bir = *(const float4*)(b_ih + k4);
  float4 biz = *(const float4*)(b_ih + 1024 + k4);
  float4 bin = *(const float4*)(b_ih + 2048 + k4);
  float4 bhr = *(const float4*)(b_hh + k4);
  float4 bhz = *(const float4*)(b_hh + 1024 + k4);
  float4 bhn = *(const float4*)(b_hh + 2048 + k4);
  f16x4 hh = *(const f16x4*)(hold_hi + (size_t)b * HD + k4);
  f16x4 hl = *(const f16x4*)(hold_lo + (size_t)b * HD + k4);
  float hov[4];
  #pragma unroll
  for (int j = 0; j < 4; ++j) hov[j] = (float)hh[j] + (float)hl[j];
  float4 ho; ho.x = hov[0]; ho.y = hov[1]; ho.z = hov[2]; ho.w = hov[3];
  float4 o;
  #define GATE(c) { \
    float rr = sigmoidf_(gir.c + bir.c + ghr.c + bhr.c); \
    float zz = sigmoidf_(giz.c + biz.c + ghz.c + bhz.c); \
    float nn = tanhf(gin.c + bin.c + rr * (ghn.c + bhn.c)); \
    o.c = (1.0f - zz) * nn + zz * ho.c; }
  GATE(x) GATE(y) GATE(z) GATE(w)
  #undef GATE
  float vv[4] = {o.x, o.y, o.z, o.w};
  f16x4 h4, l4;
  #pragma unroll
  for (int j = 0; j < 4; ++j) {
    f16 h = (f16)vv[j];
    h4[j] = h;
    l4[j] = (f16)(vv[j] - (float)h);
  }
  *(f16x4*)(hnew_hi + (size_t)b * HD + k4) = h4;
  *(f16x4*)(hnew_lo + (size_t)b * HD + k4) = l4;
}

// ================= logits GEMM v3: BM=256 x BN=64 + max/sumexp epilogue ===========
// Writes raw bias-added logits to d_out (stride OUT_ROW) and per-(row, chunk)
// {max, sum exp(v-max)} to pmax/psum [256][NCHUNK]. chunk = blockIdx.x.
__global__ __launch_bounds__(256)
void gemm_logits3_k(const f16* __restrict__ xf, const f16* __restrict__ wf,
                    const float* __restrict__ bias, float* __restrict__ out,
                    float* __restrict__ pmax, float* __restrict__ psum) {
  __shared__ f16 lb[2][2112];                 // 2 x 4224 B
  const int tid = threadIdx.x;
  const int lane = tid & 63;
  const int wave = tid >> 6;
  const int l15 = lane & 15, l4 = lane >> 4;
  const int chunk = blockIdx.x;
  const int n0 = chunk * 64;

  f32x4 acc[4][4];
  #pragma unroll
  for (int mi = 0; mi < 4; ++mi)
    #pragma unroll
    for (int ni = 0; ni < 4; ++ni) acc[mi][ni] = (f32x4){0.f, 0.f, 0.f, 0.f};

  f16x8 a_cur[4], a_nxt[4];

  #define STAGE(k0, buf) { \
    const f16* src = wf + (size_t)(n0 + lane) * 1024 + (k0) + wave * 8; \
    __builtin_amdgcn_global_load_lds((const GLOBAL_AS void*)src, \
        (LDS_AS void*)(lb[buf] + wave * 528), 16, 0, 0); }
  #define LOADA(k0, dst) { \
    _Pragma("unroll") \
    for (int mi = 0; mi < 4; ++mi) { \
      int row = wave * 64 + mi * 16 + l15; \
      dst[mi] = *(const f16x8*)(xf + (size_t)row * 1024 + (k0) + l4 * 8); \
    } }

  STAGE(0, 0);
  LOADA(0, a_cur);
  __syncthreads();

  for (int kt = 0; kt < 32; ++kt) {
    const int cur = kt & 1;
    f16x8 b[4];
    #pragma unroll
    for (int ni = 0; ni < 4; ++ni)
      b[ni] = *(const f16x8*)(lb[cur] + (size_t)l4 * 528 + (size_t)(ni * 16 + l15) * 8);
    if (kt < 31) {
      STAGE((kt + 1) * 32, cur ^ 1);
      LOADA((kt + 1) * 32, a_nxt);
    }
    #pragma unroll
    for (int mi = 0; mi < 4; ++mi)
      #pragma unroll
      for (int ni = 0; ni < 4; ++ni)
        acc[mi][ni] = __builtin_amdgcn_mfma_f32_16x16x32_f16(a_cur[mi], b[ni], acc[mi][ni], 0, 0, 0);
    __syncthreads();
    #pragma unroll
    for (int mi = 0; mi < 4; ++mi) a_cur[mi] = a_nxt[mi];
  }
  #undef STAGE
  #undef LOADA

  float bv[4];
  #pragma unroll
  for (int ni = 0; ni < 4; ++ni) bv[ni] = bias[n0 + ni * 16 + l15];

  #pragma unroll
  for (int mi = 0; mi < 4; ++mi) {
    #pragma unroll
    for (int r = 0; r < 4; ++r) {
      const int row = wave * 64 + mi * 16 + l4 * 4 + r;
      float v[4];
      #pragma unroll
      for (int ni = 0; ni < 4; ++ni) {
        v[ni] = acc[mi][ni][r] + bv[ni];
        out[(size_t)row * OUT_ROW + n0 + ni * 16 + l15] = v[ni];
      }
      // per-(row, chunk) max over 64 cols: local max4, then xor-shuffle over l15 group
      float m = fmaxf(fmaxf(v[0], v[1]), fmaxf(v[2], v[3]));
      #pragma unroll
      for (int d = 1; d < 16; d <<= 1) m = fmaxf(m, __shfl_xor(m, d, 64));
      float s = __expf(v[0] - m) + __expf(v[1] - m) + __expf(v[2] - m) + __expf(v[3] - m);
      #pragma unroll
      for (int d = 1; d < 16; d <<= 1) s += __shfl_xor(s, d, 64);
      if (l15 == 0) {
        pmax[(size_t)row * NCHUNK + chunk] = m;
        psum[(size_t)row * NCHUNK + chunk] = s;
      }
    }
  }
}

// ================= token_k: combine partials -> lse; flagged-chunk rescan; token ===
__global__ __launch_bounds__(256)
void token_k(const float* __restrict__ pmax, const float* __restrict__ psum,
             const float* __restrict__ lg,          // raw logits, row stride OUT_ROW
             const f16* __restrict__ xhi, const f16* __restrict__ xlo,
             const float* __restrict__ w, const float* __restrict__ ob,
             float* __restrict__ lse_out, int* __restrict__ tok) {
  __shared__ float sm[256];
  __shared__ float ssum[256];
  __shared__ double sd[256];
  __shared__ int sfl[16];
  __shared__ int scand[32];
  __shared__ int sflc, scnt;
  const int b = blockIdx.x;
  const int tid = threadIdx.x;
  const float* PM = pmax + (size_t)b * NCHUNK;
  const float* PS = psum + (size_t)b * NCHUNK;

  // 1) combine 500 {m,s} pairs
  float m = -3.4e38f, s = 0.0f;
  for (int c = tid; c < NCHUNK; c += 256) {
    float mc = PM[c], sc = PS[c];
    float M = fmaxf(m, mc);
    s = s * __expf(m - M) + sc * __expf(mc - M);
    m = M;
  }
  sm[tid] = m; ssum[tid] = s;
  if (tid == 0) { sflc = 0; scnt = 0; }
  __syncthreads();
  for (int off = 128; off; off >>= 1) {
    if (tid < off) {
      float m1 = sm[tid], m2 = sm[tid + off];
      float M = fmaxf(m1, m2);
      ssum[tid] = ssum[tid] * __expf(m1 - M) + ssum[tid + off] * __expf(m2 - M);
      sm[tid] = M;
    }
    __syncthreads();
  }
  const float gmax = sm[0];
  const float lse = gmax + logf(ssum[0]);
  if (tid == 0) lse_out[b] = lse;
  const float thr = gmax - THR;

  // 2) flag chunks that may contain candidates
  for (int c = tid; c < NCHUNK; c += 256) {
    if (PM[c] >= thr) {
      int p = atomicAdd(&sflc, 1);
      if (p < 16) sfl[p] = c;
    }
  }
  __syncthreads();
  const int nf = sflc < 16 ? sflc : 16;

  // 3) rescan flagged chunks from (L2-hot) raw logits; collect candidates
  const int g = tid >> 6, li = tid & 63;    // 4 chunk-groups of 64 lanes
  for (int f0 = 0; f0 < nf; f0 += 4) {
    int f = f0 + g;
    if (f < nf) {
      float v = lg[(size_t)b * OUT_ROW + sfl[f] * 64 + li];
      if (v >= thr) {
        int p = atomicAdd(&scnt, 1);
        if (p < 32) scand[p] = sfl[f] * 64 + li;
      }
    }
  }
  __syncthreads();
  const int c = scnt < 32 ? scnt : 32;

  if (c == 1) {
    if (tid == 0) tok[b] = scand[0];
    return;
  }

  // 4) exact fp64 rescue over candidates (order-independent, min-index ties)
  double best = -1.0e300; int bi = 0x7fffffff;
  for (int j = 0; j < c; ++j) {
    const int idx = scand[j];
    double p = 0.0;
    const f16* xh = xhi + (size_t)b * HD;
    const f16* xl = xlo + (size_t)b * HD;
    const float* wr = w + (size_t)idx * HD;
    for (int k = tid; k < HD; k += 256)
      p += ((double)xh[k] + (double)xl[k]) * (double)wr[k];
    sd[tid] = p;
    __syncthreads();
    for (int off = 128; off; off >>= 1) {
      if (tid < off) sd[tid] += sd[tid + off];
      __syncthreads();
    }
    if (tid == 0) sd[0] += (double)ob[idx];
    __syncthreads();
    double tot = sd[0];
    if (tot > best || (tot == best && idx < bi)) { best = tot; bi = idx; }
    __syncthreads();
  }
  if (tid == 0) tok[b] = bi;
}

// ================= final log_softmax: out[b][t][v] -= lse[t][b], one big pass ======
__global__ void sub_all_k(float* __restrict__ out, const float* __restrict__ lse_all) {
  const long total = (long)NBATCH * TSTEPS * (VOC / 4);   // 40,960,000 float4
  long i = (long)blockIdx.x * 256 + threadIdx.x;
  const long stride = (long)gridDim.x * 256;
  for (; i < total; i += stride) {
    long b = i / (TSTEPS * (VOC / 4));
    long r = i - b * (TSTEPS * (VOC / 4));
    long t = r / (VOC / 4);
    float l = lse_all[t * NBATCH + b];
    float4 v = ((float4*)out)[i];
    v.x -= l; v.y -= l; v.z -= l; v.w -= l;
    ((float4*)out)[i] = v;
  }
}

// ================= final h output: out = hi + lo =================
__global__ void combine_h_k(const f16* __restrict__ hi, const f16* __restrict__ lo,
                            float* __restrict__ o, int n4) {
  int i = blockIdx.x * 256 + threadIdx.x;
  if (i >= n4) return;
  f16x4 h = ((const f16x4*)hi)[i];
  f16x4 l = ((const f16x4*)lo)[i];
  float4 v;
  v.x = (float)h[0] + (float)l[0];
  v.y = (float)h[1] + (float)l[1];
  v.z = (float)h[2] + (float)l[2];
  v.w = (float)h[3] + (float)l[3];
  ((float4*)o)[i] = v;
}

extern "C" void kernel_launch(void* const* d_in, const int* in_sizes, int n_in,
                              void* d_out, int out_size, void* d_ws, size_t ws_size,
                              hipStream_t stream) {
  (void)in_sizes; (void)n_in; (void)out_size;
  const float* enc_hidden = (const float*)d_in[1];   // [4,256,1024]
  const float* emb   = (const float*)d_in[2];        // [32000,1024]
  const float* w_ih  = (const float*)d_in[3];        // [4,3072,1024]
  const float* w_hh  = (const float*)d_in[4];        // [4,3072,1024]
  const float* b_ih  = (const float*)d_in[5];        // [4,3072]
  const float* b_hh  = (const float*)d_in[6];        // [4,3072]
  const float* out_w = (const float*)d_in[7];        // [32000,1024]
  const float* out_b = (const float*)d_in[8];        // [32000]
  float* out = (float*)d_out;

  size_t off = 0;
  char* base = (char*)d_ws;
  #define WSALLOC(bytes) ((void*)(base + off)); off += (((size_t)(bytes)) + 255) & ~(size_t)255
  float* gg2     = (float*) WSALLOC((size_t)2 * NBATCH * 6144 * 4);  // 12.6 MB
  f16*   hs_hi   = (f16*)   WSALLOC(2 * 4 * BH * 2);                 // 4.2 MB
  f16*   hs_lo   = (f16*)   WSALLOC(2 * 4 * BH * 2);                 // 4.2 MB
  int*   tok     = (int*)   WSALLOC(1024);
  float* pmax    = (float*) WSALLOC((size_t)NBATCH * NCHUNK * 4);    // 512 KB
  float* psum    = (float*) WSALLOC((size_t)NBATCH * NCHUNK * 4);    // 512 KB
  float* lse_all = (float*) WSALLOC((size_t)TSTEPS * NBATCH * 4);    // 20 KB
  f16*   wf16    = (f16*)   WSALLOC((size_t)VOC * HD * 2);           // 65.5 MB
  #undef WSALLOC
  if (off > ws_size) return;   // fail loudly rather than corrupt

  // one-time conversions
  f32_to_f16_k<<<2048, 256, 0, stream>>>(out_w, wf16, (long)VOC * HD / 8);
  split_f32_k<<<512, 256, 0, stream>>>(enc_hidden, hs_hi, hs_lo, (long)(4 * BH / 8));
  hipMemsetAsync(tok, 0, NBATCH * 4, stream);

  int p = 0;
  for (int t = 0; t < TSTEPS; ++t) {
    f16* hp_hi = hs_hi + (size_t)p * 4 * BH;
    f16* hp_lo = hs_lo + (size_t)p * 4 * BH;
    f16* hn_hi = hs_hi + (size_t)(1 - p) * 4 * BH;
    f16* hn_lo = hs_lo + (size_t)(1 - p) * 4 * BH;

    for (int l = 0; l < 4; ++l) {
      const f16* a0hi = (l == 0) ? hs_hi : hn_hi + (size_t)(l - 1) * BH;
      const f16* a0lo = (l == 0) ? hs_lo : hn_lo + (size_t)(l - 1) * BH;
      gemm_gru_mfma4_k<<<dim3(96, 4, 2), 256, 0, stream>>>(
          a0hi, a0lo, hp_hi + (size_t)l * BH, hp_lo + (size_t)l * BH,
          emb, tok, (l == 0) ? 1 : 0,
          w_ih + (size_t)l * 3072 * HD, w_hh + (size_t)l * 3072 * HD, gg2);
      gru_gates_split2_k<<<256, 256, 0, stream>>>(
          gg2, b_ih + l * 3072, b_hh + l * 3072,
          hp_hi + (size_t)l * BH, hp_lo + (size_t)l * BH,
          hn_hi + (size_t)l * BH, hn_lo + (size_t)l * BH);
    }

    float* lg = out + (size_t)t * VOC;   // raw logits land in d_out (strided)
    gemm_logits3_k<<<NCHUNK, 256, 0, stream>>>(
        hn_hi + (size_t)3 * BH, wf16, out_b, lg, pmax, psum);
    token_k<<<NBATCH, 256, 0, stream>>>(
        pmax, psum, lg, hn_hi + (size_t)3 * BH, hn_lo + (size_t)3 * BH,
        out_w, out_b, lse_all + (size_t)t * NBATCH, tok);

    p ^= 1;
  }

  // one full-bandwidth pass: log_probs = logits - lse
  sub_all_k<<<16384, 256, 0, stream>>>(out, lse_all);

  // after 20 steps the final h splits sit in parity 0
  combine_h_k<<<1024, 256, 0, stream>>>(hs_hi, hs_lo,
                                        out + (size_t)NBATCH * TSTEPS * VOC,
                                        (int)(4 * BH / 4));
}